// Round 8
// baseline (254.685 us; speedup 1.0000x reference)
//
#include <hip/hip_runtime.h>
#include <math.h>

#define NB   4
#define H1   1056
#define W1   1920
#define H2   528
#define W2   960
#define NBLK 220    // 11*20 blocks per image, both scales
#define NBW  20
#define NF   36
#define NGAM 9801

__device__ __forceinline__ int reflect_idx(int i, int n) {
    if (i < 0) return -i - 1;
    if (i >= n) return 2 * n - i - 1;
    return i;
}

// ---------------- tables: R_GAM + ratio(a) + meanfac(a), a = 0.2 + 0.001*i
__global__ void k_rgam(float* __restrict__ rg, float* __restrict__ rt, float* __restrict__ mf) {
    int i = blockIdx.x * 256 + threadIdx.x;
    if (i < NGAM) {
        float g = (float)i * 0.001f + 0.2f;
        float l1 = lgammaf(1.0f / g);
        float l2 = lgammaf(2.0f / g);
        float l3 = lgammaf(3.0f / g);
        rg[i] = expf(2.0f * l2 - l1 - l3);
        rt[i] = expf(0.5f * (l1 - l3));
        mf[i] = expf(l2 - l1);
    }
}

// ---------------- gray: pure streaming, float4 (W1%4==0). y = round(dot(rgb)*255)
__global__ void k_gray(const float4* __restrict__ x, float4* __restrict__ y) {
    int idx = blockIdx.x * 256 + threadIdx.x;
    const int W4 = W1 / 4;
    const int total = NB * H1 * W4;
    if (idx >= total) return;
    int w4 = idx % W4;
    int t  = idx / W4;
    int h  = t % H1;
    int b  = t / H1;
    size_t base = ((size_t)(b * 3) * 1080 + h) * W4 + w4;
    float4 r  = x[base];
    float4 g  = x[base + (size_t)1080 * W4];
    float4 bb = x[base + (size_t)2 * 1080 * W4];
    float4 o;
    o.x = rintf((0.299f * r.x + 0.587f * g.x + 0.114f * bb.x) * 255.0f);
    o.y = rintf((0.299f * r.y + 0.587f * g.y + 0.114f * bb.y) * 255.0f);
    o.z = rintf((0.299f * r.z + 0.587f * g.z + 0.114f * bb.z) * 255.0f);
    o.w = rintf((0.299f * r.w + 0.587f * g.w + 0.114f * bb.w) * 255.0f);
    y[idx] = o;
}

// ---------------- fused bicubic half-resize (H then W pass, in LDS): y -> half
__device__ const float RW8[8] = {-0.01171875f, -0.03515625f, 0.11328125f, 0.43359375f,
                                  0.43359375f,  0.11328125f, -0.03515625f, -0.01171875f};

__global__ __launch_bounds__(256) void k_resize(const float* __restrict__ y,
                                                float* __restrict__ half) {
    __shared__ float yt[70][72];
    __shared__ float vv[32][72];
    int tid = threadIdx.y * 32 + threadIdx.x;
    int b = blockIdx.z;
    int j0 = blockIdx.x * 32, i0 = blockIdx.y * 32;
    const float* py = y + (size_t)b * H1 * W1;
    int rbase = 2 * i0 - 3, cbase = 2 * j0 - 3;

    for (int t = tid; t < 70 * 70; t += 256) {
        int r = t / 70, c = t % 70;
        int gr = reflect_idx(rbase + r, H1);
        int gc = reflect_idx(cbase + c, W1);
        yt[r][c] = py[(size_t)gr * W1 + gc] / 255.0f;
    }
    __syncthreads();

    for (int t = tid; t < 32 * 70; t += 256) {
        int i = t / 70, c = t % 70;
        float acc = 0.0f;
        #pragma unroll
        for (int p = 0; p < 8; p++) acc += RW8[p] * yt[2 * i + p][c];
        vv[i][c] = acc;
    }
    __syncthreads();

    float* ph = half + (size_t)b * H2 * W2;
    for (int t = tid; t < 1024; t += 256) {
        int i = t >> 5, j = t & 31;
        int oy = i0 + i, ox = j0 + j;
        if (oy < H2 && ox < W2) {
            float acc = 0.0f;
            #pragma unroll
            for (int p = 0; p < 8; p++) acc += RW8[p] * vv[i][2 * j + p];
            ph[(size_t)oy * W2 + ox] = acc * 255.0f;
        }
    }
}

// ---------------- FUSED MSCN + AGGD features: one 96x96 (48x48) block per workgroup.
// Stage (BS+6)^2 y-tile -> separable 7-tap conv (h-pass to h1/h2, v-pass to regs)
// -> write norm in-place over y-tile -> feats (register-window AGGD + table argmin).
// norm never goes to HBM.
template <int BS, int FOFF, int NT>
__global__ __launch_bounds__(NT) void k_fused(const float* __restrict__ src,
                                              const float* __restrict__ rgam,
                                              const float* __restrict__ ratio_t,
                                              const float* __restrict__ meanfac_t,
                                              float* __restrict__ feats, int H, int W) {
    constexpr int TS    = BS + 6;         // staged tile incl. 3-px halo
    constexpr int YP    = BS + 8;         // y-tile pitch (mult of 4)
    constexpr int HP    = BS + 4;         // h1/h2 pitch (mult of 4)
    constexpr int CG    = BS / 4;         // 4-col groups per row
    constexpr int VITER = (BS * CG) / NT; // v-pass items/thread: 96:3, 48:1 (exact)
    constexpr int SPAN  = (BS * BS) / NT; // feats cols/thread: 12 / 4
    constexpr int TPR   = BS / SPAN;      // feats threads/row: 8 / 12
    constexpr int NW    = NT / 64;

    __shared__ __align__(16) float yt[TS * YP];
    __shared__ __align__(16) float h1[TS * HP];
    __shared__ __align__(16) float h2[TS * HP];
    __shared__ float gw1[8];
    __shared__ float wred[25][NW];
    __shared__ float sums[25];
    __shared__ float srn[5], sls[5], srs[5];
    __shared__ float wargd[5][NW];
    __shared__ int   wargi[5][NW];

    int g  = blockIdx.x;          // b*NBLK + r
    int b  = g / NBLK;
    int r  = g % NBLK;
    int bh = r / NBW, bw = r % NBW;
    int row0 = bh * BS, col0 = bw * BS;
    const float* p = src + (size_t)b * H * W;
    int tid = threadIdx.x;
    int lane = tid & 63, wv = tid >> 6;

    if (tid < 7) {
        double s = 7.0 / 6.0;
        double sum = 0.0;
        #pragma unroll
        for (int k = 0; k < 7; k++) sum += exp(-(double)((k - 3) * (k - 3)) / (2.0 * s * s));
        double e = exp(-(double)((tid - 3) * (tid - 3)) / (2.0 * s * s));
        gw1[tid] = (float)(e / sum);
    }

    // stage y tile with replicate clamp
    for (int t = tid; t < TS * TS; t += NT) {
        int rr = t / TS, cc = t % TS;
        int gr = row0 - 3 + rr; gr = gr < 0 ? 0 : (gr >= H ? H - 1 : gr);
        int gc = col0 - 3 + cc; gc = gc < 0 ? 0 : (gc >= W ? W - 1 : gc);
        yt[rr * YP + cc] = p[(size_t)gr * W + gc];
    }
    __syncthreads();

    // h-pass: all TS rows, BS cols (4-col groups)
    for (int t = tid; t < TS * CG; t += NT) {
        int rr = t / CG, c0 = (t % CG) * 4;
        const float* yrow = &yt[rr * YP + c0];
        float4 f0 = *(const float4*)yrow;
        float4 f1 = *(const float4*)(yrow + 4);
        float2 f2 = *(const float2*)(yrow + 8);
        float v[10] = {f0.x, f0.y, f0.z, f0.w, f1.x, f1.y, f1.z, f1.w, f2.x, f2.y};
        float s1[4] = {0, 0, 0, 0}, s2[4] = {0, 0, 0, 0};
        #pragma unroll
        for (int k = 0; k < 7; k++) {
            float w = gw1[k];
            #pragma unroll
            for (int s = 0; s < 4; s++) {
                float vv = v[s + k];
                s1[s] += w * vv;
                s2[s] += w * vv * vv;
            }
        }
        *(float4*)&h1[rr * HP + c0] = make_float4(s1[0], s1[1], s1[2], s1[3]);
        *(float4*)&h2[rr * HP + c0] = make_float4(s2[0], s2[1], s2[2], s2[3]);
    }
    __syncthreads();

    // v-pass: compute norm into registers (exact NT*VITER == BS*CG items)
    float nrmreg[VITER][4];
    #pragma unroll
    for (int it = 0; it < VITER; it++) {
        int t = tid + it * NT;
        int rr = t / CG, c0 = (t % CG) * 4;
        float m1[4] = {0, 0, 0, 0}, m2[4] = {0, 0, 0, 0};
        #pragma unroll
        for (int k = 0; k < 7; k++) {
            float w = gw1[k];
            float4 a = *(const float4*)&h1[(rr + k) * HP + c0];
            float4 bq = *(const float4*)&h2[(rr + k) * HP + c0];
            m1[0] += w * a.x;  m1[1] += w * a.y;  m1[2] += w * a.z;  m1[3] += w * a.w;
            m2[0] += w * bq.x; m2[1] += w * bq.y; m2[2] += w * bq.z; m2[3] += w * bq.w;
        }
        #pragma unroll
        for (int j = 0; j < 4; j++) {
            float cx  = yt[(rr + 3) * YP + c0 + 3 + j];
            float sig = sqrtf(fabsf(m2[j] - m1[j] * m1[j]));
            nrmreg[it][j] = (cx - m1[j]) / (sig + 1.0f);
        }
    }
    __syncthreads();
    #pragma unroll
    for (int it = 0; it < VITER; it++) {
        int t = tid + it * NT;
        int rr = t / CG, c0 = (t % CG) * 4;
        *(float4*)&yt[rr * YP + c0] = make_float4(nrmreg[it][0], nrmreg[it][1],
                                                  nrmreg[it][2], nrmreg[it][3]);
    }
    __syncthreads();

    // ---- feats phase: x = norm at yt, pitch YP, rows/cols [0,BS)
    int i  = tid / TPR;
    int c0 = (tid % TPR) * SPAN;
    int rowc = i * YP;
    int rowm = ((i == 0) ? BS - 1 : i - 1) * YP;
    float cv[SPAN], mv[SPAN];
    #pragma unroll
    for (int k = 0; k < SPAN / 4; k++) {
        *(float4*)&cv[4 * k] = *(const float4*)&yt[rowc + c0 + 4 * k];
        *(float4*)&mv[4 * k] = *(const float4*)&yt[rowm + c0 + 4 * k];
    }
    float cprev  = yt[rowc + (c0 == 0 ? BS - 1 : c0 - 1)];
    float mleft  = yt[rowm + (c0 == 0 ? BS - 1 : c0 - 1)];
    float mright = yt[rowm + (c0 + SPAN == BS ? 0 : c0 + SPAN)];

    float sn[5] = {0, 0, 0, 0, 0}, sp[5] = {0, 0, 0, 0, 0};
    float cn[5] = {0, 0, 0, 0, 0}, cp[5] = {0, 0, 0, 0, 0};
    float sa[5] = {0, 0, 0, 0, 0};

    #pragma unroll
    for (int k = 0; k < SPAN; k++) {
        float v0 = cv[k];
        float v[5];
        v[0] = v0;
        v[1] = v0 * (k > 0 ? cv[k - 1] : cprev);
        v[2] = v0 * mv[k];
        v[3] = v0 * (k > 0 ? mv[k - 1] : mleft);
        v[4] = v0 * (k + 1 < SPAN ? mv[k + 1] : mright);
        #pragma unroll
        for (int s = 0; s < 5; s++) {
            float vv = v[s];
            float vn = fminf(vv, 0.0f);
            float vp = fmaxf(vv, 0.0f);
            sn[s] += vn * vn;
            sp[s] += vp * vp;
            cn[s] += (vv < 0.0f) ? 1.0f : 0.0f;
            cp[s] += (vv > 0.0f) ? 1.0f : 0.0f;
            sa[s] += fabsf(vv);
        }
    }

    #pragma unroll
    for (int s = 0; s < 5; s++) {
        float vals[5] = {sn[s], sp[s], cn[s], cp[s], sa[s]};
        #pragma unroll
        for (int m = 0; m < 5; m++) {
            float v = vals[m];
            #pragma unroll
            for (int off = 32; off > 0; off >>= 1) v += __shfl_down(v, off, 64);
            if (lane == 0) wred[s * 5 + m][wv] = v;
        }
    }
    __syncthreads();

    if (tid < 25) {
        float s = 0.0f;
        #pragma unroll
        for (int w = 0; w < NW; w++) s += wred[tid][w];
        sums[tid] = s;
    }
    __syncthreads();

    if (tid < 5) {
        int s = tid;
        float SN = sums[s * 5 + 0], SP = sums[s * 5 + 1];
        float CN = sums[s * 5 + 2], CP = sums[s * 5 + 3], SA = sums[s * 5 + 4];
        float ls = sqrtf(SN / CN);
        float rs = sqrtf(SP / CP);
        float gh = ls / rs;
        float Nn = (float)(BS * BS);
        float am = SA / Nn;
        float rhat = (am * am) / ((SN + SP) / Nn);
        float g2 = gh * gh;
        float rn = rhat * (g2 * gh + 1.0f) * (gh + 1.0f) / ((g2 + 1.0f) * (g2 + 1.0f));
        srn[s] = rn; sls[s] = ls; srs[s] = rs;
    }
    __syncthreads();

    float bd[5] = {1e30f, 1e30f, 1e30f, 1e30f, 1e30f};
    int   bi[5] = {0, 0, 0, 0, 0};
    float t0 = srn[0], t1 = srn[1], t2 = srn[2], t3 = srn[3], t4 = srn[4];
    for (int idx = tid; idx < NGAM; idx += NT) {
        float rg = rgam[idx];
        float d0 = (rg - t0) * (rg - t0);
        float d1 = (rg - t1) * (rg - t1);
        float d2 = (rg - t2) * (rg - t2);
        float d3 = (rg - t3) * (rg - t3);
        float d4 = (rg - t4) * (rg - t4);
        if (d0 < bd[0]) { bd[0] = d0; bi[0] = idx; }
        if (d1 < bd[1]) { bd[1] = d1; bi[1] = idx; }
        if (d2 < bd[2]) { bd[2] = d2; bi[2] = idx; }
        if (d3 < bd[3]) { bd[3] = d3; bi[3] = idx; }
        if (d4 < bd[4]) { bd[4] = d4; bi[4] = idx; }
    }
    #pragma unroll
    for (int s = 0; s < 5; s++) {
        float d = bd[s];
        int   ii = bi[s];
        #pragma unroll
        for (int off = 32; off > 0; off >>= 1) {
            float od = __shfl_down(d, off, 64);
            int   oi = __shfl_down(ii, off, 64);
            if (od < d || (od == d && oi < ii)) { d = od; ii = oi; }
        }
        if (lane == 0) { wargd[s][wv] = d; wargi[s][wv] = ii; }
    }
    __syncthreads();

    if (tid < 5) {
        int s = tid;
        float d = wargd[s][0]; int ix = wargi[s][0];
        #pragma unroll
        for (int w = 1; w < NW; w++) {
            float od = wargd[s][w]; int oi = wargi[s][w];
            if (od < d || (od == d && oi < ix)) { d = od; ix = oi; }
        }
        float a = (float)ix * 0.001f + 0.2f;
        float ratio = ratio_t[ix];
        float bl = sls[s] * ratio;
        float br = srs[s] * ratio;
        float* fp = feats + (size_t)g * NF + FOFF;
        if (s == 0) {
            fp[0] = a; fp[1] = 0.5f * (bl + br);
        } else {
            float mn = (br - bl) * meanfac_t[ix];
            int base = 2 + (s - 1) * 4;
            fp[base] = a; fp[base + 1] = mn; fp[base + 2] = bl; fp[base + 3] = br;
        }
    }
}

// ---------------- per-batch stats: cov via transposed dist + 3x3 register tiles,
// then no-pivot Gauss-Jordan (M is SPD), f32 throughout.
__global__ __launch_bounds__(256) void k_stats(const float* __restrict__ feats,
                                               const float* __restrict__ mu_pris,
                                               const float* __restrict__ cov_pris,
                                               float* __restrict__ out) {
    __shared__ float dist[NBLK * NF];
    __shared__ __align__(16) float distT[NF][228];
    __shared__ float mu[NF];
    __shared__ float M[NF][NF + 1];
    __shared__ float facs[NF];
    __shared__ float dd[NF];

    int b = blockIdx.x, tid = threadIdx.x;
    for (int t = tid; t < NBLK * NF; t += 256) dist[t] = feats[(size_t)b * NBLK * NF + t];
    __syncthreads();
    if (tid < NF) {
        float s = 0.0f;
        for (int n = 0; n < NBLK; n++) s += dist[n * NF + tid];
        mu[tid] = s / (float)NBLK;
    }
    __syncthreads();
    for (int t = tid; t < NF * NBLK; t += 256) {
        int f = t / NBLK, n = t % NBLK;
        distT[f][n] = dist[n * NF + f] - mu[f];
    }
    __syncthreads();

    if (tid < 144) {
        int f0 = (tid / 12) * 3, g0 = (tid % 12) * 3;
        float acc[3][3] = {{0,0,0},{0,0,0},{0,0,0}};
        for (int n = 0; n < NBLK; n += 4) {
            float4 A[3], B[3];
            #pragma unroll
            for (int i = 0; i < 3; i++) A[i] = *(const float4*)&distT[f0 + i][n];
            #pragma unroll
            for (int j = 0; j < 3; j++) B[j] = *(const float4*)&distT[g0 + j][n];
            #pragma unroll
            for (int i = 0; i < 3; i++)
                #pragma unroll
                for (int j = 0; j < 3; j++)
                    acc[i][j] += A[i].x * B[j].x + A[i].y * B[j].y
                               + A[i].z * B[j].z + A[i].w * B[j].w;
        }
        const float* cp = cov_pris + (size_t)b * NF * NF;
        #pragma unroll
        for (int i = 0; i < 3; i++)
            #pragma unroll
            for (int j = 0; j < 3; j++) {
                int f = f0 + i, gg = g0 + j;
                M[f][gg] = (cp[f * NF + gg] + acc[i][j] / (float)(NBLK - 1)) * 0.5f;
            }
    }
    if (tid < NF) {
        float d = mu_pris[b * NF + tid] - mu[tid];
        dd[tid] = d;
        M[tid][NF] = d;
    }
    __syncthreads();

    for (int k = 0; k < NF; k++) {
        if (tid < NF && tid != k) facs[tid] = M[tid][k] / M[k][k];
        __syncthreads();
        for (int t = tid; t < NF * (NF + 1); t += 256) {
            int i = t / (NF + 1), j = t % (NF + 1);
            if (i != k && j > k) M[i][j] -= facs[i] * M[k][j];
        }
        __syncthreads();
    }

    if (tid < 64) {
        double c = (tid < NF) ? (double)dd[tid] * ((double)M[tid][NF] / (double)M[tid][tid]) : 0.0;
        #pragma unroll
        for (int off = 32; off > 0; off >>= 1) c += __shfl_down(c, off, 64);
        if (tid == 0) out[b] = (float)sqrt(c);
    }
}

extern "C" void kernel_launch(void* const* d_in, const int* in_sizes, int n_in,
                              void* d_out, int out_size, void* d_ws, size_t ws_size,
                              hipStream_t stream) {
    const float* x        = (const float*)d_in[0];
    const float* mu_pris  = (const float*)d_in[1];
    const float* cov_pris = (const float*)d_in[2];
    float* out = (float*)d_out;
    float* ws  = (float*)d_ws;

    float* y     = ws;                          // NB*H1*W1 = 8,110,080
    float* half  = y + (size_t)NB * H1 * W1;    // NB*H2*W2 = 2,027,520
    float* rgam  = half + (size_t)NB * H2 * W2; // 9801
    float* ratio = rgam + NGAM;                 // 9801
    float* mfac  = ratio + NGAM;                // 9801
    float* feats = mfac + NGAM;                 // NB*220*36 = 31,680

    k_rgam<<<(NGAM + 255) / 256, 256, 0, stream>>>(rgam, ratio, mfac);
    k_gray<<<(NB * H1 * (W1 / 4) + 255) / 256, 256, 0, stream>>>((const float4*)x, (float4*)y);

    k_fused<96, 0, 768><<<NB * NBLK, 768, 0, stream>>>(y, rgam, ratio, mfac, feats, H1, W1);

    dim3 thr(32, 8);
    k_resize<<<dim3(W2 / 32, (H2 + 31) / 32, NB), thr, 0, stream>>>(y, half);

    k_fused<48, 18, 576><<<NB * NBLK, 576, 0, stream>>>(half, rgam, ratio, mfac, feats, H2, W2);

    k_stats<<<NB, 256, 0, stream>>>(feats, mu_pris, cov_pris, out);
}

// Round 9
// 223.584 us; speedup vs baseline: 1.1391x; 1.1391x over previous
//
#include <hip/hip_runtime.h>
#include <math.h>

#define NB   4
#define H1   1056
#define W1   1920
#define H2   528
#define W2   960
#define NBLK 220    // 11*20 blocks per image, both scales
#define NBW  20
#define NF   36
#define NGAM 9801

__device__ __forceinline__ int reflect_idx(int i, int n) {
    if (i < 0) return -i - 1;
    if (i >= n) return 2 * n - i - 1;
    return i;
}

// ---------------- gray (float4 streaming) + R_GAM/ratio/meanfac tables in one launch.
// Blocks [0, NGB) do gray; blocks [NGB, NGB+39) build the 9801-entry tables.
__global__ void k_gray_rgam(const float4* __restrict__ x, float4* __restrict__ y,
                            float* __restrict__ rg, float* __restrict__ rt,
                            float* __restrict__ mf) {
    const int W4 = W1 / 4;
    const int gtotal = NB * H1 * W4;
    int idx = blockIdx.x * 256 + threadIdx.x;
    if (idx < gtotal) {
        int w4 = idx % W4;
        int t  = idx / W4;
        int h  = t % H1;
        int b  = t / H1;
        size_t base = ((size_t)(b * 3) * 1080 + h) * W4 + w4;
        float4 r  = x[base];
        float4 g  = x[base + (size_t)1080 * W4];
        float4 bb = x[base + (size_t)2 * 1080 * W4];
        float4 o;
        o.x = rintf((0.299f * r.x + 0.587f * g.x + 0.114f * bb.x) * 255.0f);
        o.y = rintf((0.299f * r.y + 0.587f * g.y + 0.114f * bb.y) * 255.0f);
        o.z = rintf((0.299f * r.z + 0.587f * g.z + 0.114f * bb.z) * 255.0f);
        o.w = rintf((0.299f * r.w + 0.587f * g.w + 0.114f * bb.w) * 255.0f);
        y[idx] = o;
    } else {
        int i = idx - gtotal;
        if (i < NGAM) {
            float g = (float)i * 0.001f + 0.2f;
            float l1 = lgammaf(1.0f / g);
            float l2 = lgammaf(2.0f / g);
            float l3 = lgammaf(3.0f / g);
            rg[i] = expf(2.0f * l2 - l1 - l3);
            rt[i] = expf(0.5f * (l1 - l3));
            mf[i] = expf(l2 - l1);
        }
    }
}

// ---------------- MSCN, register-blocked separable 7-tap, single-channel input.
// 32x32 output tile, block (32,8); h-pass 4 cols via b128; v-pass 4 rows/thread.
__global__ __launch_bounds__(256) void k_mscn(const float* __restrict__ src,
                                              float* __restrict__ out, int H, int W) {
    __shared__ float tile[38][40];
    __shared__ float h1s[38][36];
    __shared__ float h2s[38][36];
    __shared__ float gw1[8];

    int tx = threadIdx.x;            // 0..31
    int ty = threadIdx.y;            // 0..7
    int tid = ty * 32 + tx;

    if (tid < 7) {
        double s = 7.0 / 6.0;
        double sum = 0.0;
        #pragma unroll
        for (int k = 0; k < 7; k++) sum += exp(-(double)((k - 3) * (k - 3)) / (2.0 * s * s));
        double e = exp(-(double)((tid - 3) * (tid - 3)) / (2.0 * s * s));
        gw1[tid] = (float)(e / sum);
    }

    int b = blockIdx.z;
    const float* p = src + (size_t)b * H * W;
    int ox0 = blockIdx.x * 32, oy0 = blockIdx.y * 32;

    for (int t = tid; t < 38 * 38; t += 256) {
        int r = t / 38, c = t % 38;
        int gr = oy0 - 3 + r; gr = gr < 0 ? 0 : (gr >= H ? H - 1 : gr);
        int gc = ox0 - 3 + c; gc = gc < 0 ? 0 : (gc >= W ? W - 1 : gc);
        tile[r][c] = p[(size_t)gr * W + gc];
    }
    __syncthreads();

    // h-pass: 38 rows x 8 groups of 4 cols
    for (int t = tid; t < 38 * 8; t += 256) {
        int r = t / 8, c0 = (t % 8) * 4;
        float4 f0 = *(const float4*)&tile[r][c0];
        float4 f1 = *(const float4*)&tile[r][c0 + 4];
        float2 f2 = *(const float2*)&tile[r][c0 + 8];
        float v[10] = {f0.x, f0.y, f0.z, f0.w, f1.x, f1.y, f1.z, f1.w, f2.x, f2.y};
        float s1[4] = {0, 0, 0, 0}, s2[4] = {0, 0, 0, 0};
        #pragma unroll
        for (int k = 0; k < 7; k++) {
            float w = gw1[k];
            #pragma unroll
            for (int s = 0; s < 4; s++) {
                float vv = v[s + k];
                s1[s] += w * vv;
                s2[s] += w * vv * vv;
            }
        }
        *(float4*)&h1s[r][c0] = make_float4(s1[0], s1[1], s1[2], s1[3]);
        *(float4*)&h2s[r][c0] = make_float4(s2[0], s2[1], s2[2], s2[3]);
    }
    __syncthreads();

    // v-pass: 4 consecutive rows per thread (register window)
    int ly0 = ty * 4;
    float a1[10], a2[10];
    #pragma unroll
    for (int k = 0; k < 10; k++) { a1[k] = h1s[ly0 + k][tx]; a2[k] = h2s[ly0 + k][tx]; }
    float* q = out + (size_t)b * H * W;
    #pragma unroll
    for (int s = 0; s < 4; s++) {
        int oy = oy0 + ly0 + s, ox = ox0 + tx;
        if (oy < H) {
            float m1 = 0.0f, m2 = 0.0f;
            #pragma unroll
            for (int k = 0; k < 7; k++) {
                float w = gw1[k];
                m1 += w * a1[s + k];
                m2 += w * a2[s + k];
            }
            float sig = sqrtf(fabsf(m2 - m1 * m1));
            q[(size_t)oy * W + ox] = (tile[ly0 + s + 3][tx + 3] - m1) / (sig + 1.0f);
        }
    }
}

// ---------------- fused bicubic half-resize (H then W pass, in LDS): y -> half
__device__ const float RW8[8] = {-0.01171875f, -0.03515625f, 0.11328125f, 0.43359375f,
                                  0.43359375f,  0.11328125f, -0.03515625f, -0.01171875f};

__global__ __launch_bounds__(256) void k_resize(const float* __restrict__ y,
                                                float* __restrict__ half) {
    __shared__ float yt[70][72];
    __shared__ float vv[32][72];
    int tid = threadIdx.y * 32 + threadIdx.x;
    int b = blockIdx.z;
    int j0 = blockIdx.x * 32, i0 = blockIdx.y * 32;
    const float* py = y + (size_t)b * H1 * W1;
    int rbase = 2 * i0 - 3, cbase = 2 * j0 - 3;

    for (int t = tid; t < 70 * 70; t += 256) {
        int r = t / 70, c = t % 70;
        int gr = reflect_idx(rbase + r, H1);
        int gc = reflect_idx(cbase + c, W1);
        yt[r][c] = py[(size_t)gr * W1 + gc] / 255.0f;
    }
    __syncthreads();

    for (int t = tid; t < 32 * 70; t += 256) {
        int i = t / 70, c = t % 70;
        float acc = 0.0f;
        #pragma unroll
        for (int p = 0; p < 8; p++) acc += RW8[p] * yt[2 * i + p][c];
        vv[i][c] = acc;
    }
    __syncthreads();

    float* ph = half + (size_t)b * H2 * W2;
    for (int t = tid; t < 1024; t += 256) {
        int i = t >> 5, j = t & 31;
        int oy = i0 + i, ox = j0 + j;
        if (oy < H2 && ox < W2) {
            float acc = 0.0f;
            #pragma unroll
            for (int p = 0; p < 8; p++) acc += RW8[p] * vv[i][2 * j + p];
            ph[(size_t)oy * W2 + ox] = acc * 255.0f;
        }
    }
}

// ---------------- per-block AGGD features, register-window inner loop.
// NT=768 (96) / 576 (48): more waves per block halves the per-block serial chain;
// each thread owns SPAN consecutive cols of one row, windows in registers.
template <int BS, int FOFF, int NT>
__global__ __launch_bounds__(NT) void k_feats(const float* __restrict__ norm,
                                              const float* __restrict__ rgam,
                                              const float* __restrict__ ratio_t,
                                              const float* __restrict__ meanfac_t,
                                              float* __restrict__ feats, int H, int W) {
    constexpr int NW    = NT / 64;
    constexpr int PITCH = BS + 4;
    constexpr int SPAN  = (BS * BS) / NT;   // 12 (96/768) / 4 (48/576)
    constexpr int TPR   = BS / SPAN;        // threads per row: 8 / 12
    static_assert(SPAN % 4 == 0 && TPR * SPAN == BS, "layout");
    __shared__ __align__(16) float x[BS * PITCH];
    __shared__ float wred[25][NW];
    __shared__ float sums[25];
    __shared__ float srn[5], sls[5], srs[5];
    __shared__ float wargd[5][NW];
    __shared__ int   wargi[5][NW];

    int g  = blockIdx.x;          // b*NBLK + r
    int b  = g / NBLK;
    int r  = g % NBLK;
    int bh = r / NBW, bw = r % NBW;
    const float* p = norm + (size_t)b * H * W + (size_t)(bh * BS) * W + (size_t)(bw * BS);
    int tid = threadIdx.x;
    int lane = tid & 63, wv = tid >> 6;

    for (int t = tid; t < BS * BS; t += NT) {
        int i = t / BS, j = t - i * BS;
        x[i * PITCH + j] = p[(size_t)i * W + j];
    }
    __syncthreads();

    // per-thread register windows
    int i  = tid / TPR;
    int c0 = (tid % TPR) * SPAN;
    int rowc = i * PITCH;
    int rowm = ((i == 0) ? BS - 1 : i - 1) * PITCH;
    float cv[SPAN], mv[SPAN];
    #pragma unroll
    for (int k = 0; k < SPAN / 4; k++) {
        *(float4*)&cv[4 * k] = *(const float4*)&x[rowc + c0 + 4 * k];
        *(float4*)&mv[4 * k] = *(const float4*)&x[rowm + c0 + 4 * k];
    }
    float cprev  = x[rowc + (c0 == 0 ? BS - 1 : c0 - 1)];
    float mleft  = x[rowm + (c0 == 0 ? BS - 1 : c0 - 1)];
    float mright = x[rowm + (c0 + SPAN == BS ? 0 : c0 + SPAN)];

    float sn[5] = {0, 0, 0, 0, 0}, sp[5] = {0, 0, 0, 0, 0};
    float cn[5] = {0, 0, 0, 0, 0}, cp[5] = {0, 0, 0, 0, 0};
    float sa[5] = {0, 0, 0, 0, 0};

    #pragma unroll
    for (int k = 0; k < SPAN; k++) {
        float v0 = cv[k];
        float v[5];
        v[0] = v0;
        v[1] = v0 * (k > 0 ? cv[k - 1] : cprev);
        v[2] = v0 * mv[k];
        v[3] = v0 * (k > 0 ? mv[k - 1] : mleft);
        v[4] = v0 * (k + 1 < SPAN ? mv[k + 1] : mright);
        #pragma unroll
        for (int s = 0; s < 5; s++) {
            float vv = v[s];
            float vn = fminf(vv, 0.0f);
            float vp = fmaxf(vv, 0.0f);
            sn[s] += vn * vn;
            sp[s] += vp * vp;
            cn[s] += (vv < 0.0f) ? 1.0f : 0.0f;
            cp[s] += (vv > 0.0f) ? 1.0f : 0.0f;
            sa[s] += fabsf(vv);
        }
    }

    #pragma unroll
    for (int s = 0; s < 5; s++) {
        float vals[5] = {sn[s], sp[s], cn[s], cp[s], sa[s]};
        #pragma unroll
        for (int m = 0; m < 5; m++) {
            float v = vals[m];
            #pragma unroll
            for (int off = 32; off > 0; off >>= 1) v += __shfl_down(v, off, 64);
            if (lane == 0) wred[s * 5 + m][wv] = v;
        }
    }
    __syncthreads();

    if (tid < 25) {
        float s = 0.0f;
        #pragma unroll
        for (int w = 0; w < NW; w++) s += wred[tid][w];
        sums[tid] = s;
    }
    __syncthreads();

    if (tid < 5) {
        int s = tid;
        float SN = sums[s * 5 + 0], SP = sums[s * 5 + 1];
        float CN = sums[s * 5 + 2], CP = sums[s * 5 + 3], SA = sums[s * 5 + 4];
        float ls = sqrtf(SN / CN);
        float rs = sqrtf(SP / CP);
        float gh = ls / rs;
        float Nn = (float)(BS * BS);
        float am = SA / Nn;
        float rhat = (am * am) / ((SN + SP) / Nn);
        float g2 = gh * gh;
        float rn = rhat * (g2 * gh + 1.0f) * (gh + 1.0f) / ((g2 + 1.0f) * (g2 + 1.0f));
        srn[s] = rn; sls[s] = ls; srs[s] = rs;
    }
    __syncthreads();

    float bd[5] = {1e30f, 1e30f, 1e30f, 1e30f, 1e30f};
    int   bi[5] = {0, 0, 0, 0, 0};
    float t0 = srn[0], t1 = srn[1], t2 = srn[2], t3 = srn[3], t4 = srn[4];
    for (int idx = tid; idx < NGAM; idx += NT) {
        float rg = rgam[idx];
        float d0 = (rg - t0) * (rg - t0);
        float d1 = (rg - t1) * (rg - t1);
        float d2 = (rg - t2) * (rg - t2);
        float d3 = (rg - t3) * (rg - t3);
        float d4 = (rg - t4) * (rg - t4);
        if (d0 < bd[0]) { bd[0] = d0; bi[0] = idx; }
        if (d1 < bd[1]) { bd[1] = d1; bi[1] = idx; }
        if (d2 < bd[2]) { bd[2] = d2; bi[2] = idx; }
        if (d3 < bd[3]) { bd[3] = d3; bi[3] = idx; }
        if (d4 < bd[4]) { bd[4] = d4; bi[4] = idx; }
    }
    #pragma unroll
    for (int s = 0; s < 5; s++) {
        float d = bd[s];
        int   ii = bi[s];
        #pragma unroll
        for (int off = 32; off > 0; off >>= 1) {
            float od = __shfl_down(d, off, 64);
            int   oi = __shfl_down(ii, off, 64);
            if (od < d || (od == d && oi < ii)) { d = od; ii = oi; }
        }
        if (lane == 0) { wargd[s][wv] = d; wargi[s][wv] = ii; }
    }
    __syncthreads();

    if (tid < 5) {
        int s = tid;
        float d = wargd[s][0]; int ix = wargi[s][0];
        #pragma unroll
        for (int w = 1; w < NW; w++) {
            float od = wargd[s][w]; int oi = wargi[s][w];
            if (od < d || (od == d && oi < ix)) { d = od; ix = oi; }
        }
        float a = (float)ix * 0.001f + 0.2f;
        float ratio = ratio_t[ix];
        float bl = sls[s] * ratio;
        float br = srs[s] * ratio;
        float* fp = feats + (size_t)g * NF + FOFF;
        if (s == 0) {
            fp[0] = a; fp[1] = 0.5f * (bl + br);
        } else {
            float mn = (br - bl) * meanfac_t[ix];
            int base = 2 + (s - 1) * 4;
            fp[base] = a; fp[base + 1] = mn; fp[base + 2] = bl; fp[base + 3] = br;
        }
    }
}

// ---------------- per-batch stats: cov via transposed dist + 3x3 register tiles,
// then no-pivot Gauss-Jordan (M is SPD), f32 throughout.
__global__ __launch_bounds__(256) void k_stats(const float* __restrict__ feats,
                                               const float* __restrict__ mu_pris,
                                               const float* __restrict__ cov_pris,
                                               float* __restrict__ out) {
    __shared__ float dist[NBLK * NF];
    __shared__ __align__(16) float distT[NF][228];
    __shared__ float mu[NF];
    __shared__ float M[NF][NF + 1];
    __shared__ float facs[NF];
    __shared__ float dd[NF];

    int b = blockIdx.x, tid = threadIdx.x;
    for (int t = tid; t < NBLK * NF; t += 256) dist[t] = feats[(size_t)b * NBLK * NF + t];
    __syncthreads();
    if (tid < NF) {
        float s = 0.0f;
        for (int n = 0; n < NBLK; n++) s += dist[n * NF + tid];
        mu[tid] = s / (float)NBLK;
    }
    __syncthreads();
    for (int t = tid; t < NF * NBLK; t += 256) {
        int f = t / NBLK, n = t % NBLK;
        distT[f][n] = dist[n * NF + f] - mu[f];
    }
    __syncthreads();

    if (tid < 144) {
        int f0 = (tid / 12) * 3, g0 = (tid % 12) * 3;
        float acc[3][3] = {{0,0,0},{0,0,0},{0,0,0}};
        for (int n = 0; n < NBLK; n += 4) {
            float4 A[3], B[3];
            #pragma unroll
            for (int i = 0; i < 3; i++) A[i] = *(const float4*)&distT[f0 + i][n];
            #pragma unroll
            for (int j = 0; j < 3; j++) B[j] = *(const float4*)&distT[g0 + j][n];
            #pragma unroll
            for (int i = 0; i < 3; i++)
                #pragma unroll
                for (int j = 0; j < 3; j++)
                    acc[i][j] += A[i].x * B[j].x + A[i].y * B[j].y
                               + A[i].z * B[j].z + A[i].w * B[j].w;
        }
        const float* cp = cov_pris + (size_t)b * NF * NF;
        #pragma unroll
        for (int i = 0; i < 3; i++)
            #pragma unroll
            for (int j = 0; j < 3; j++) {
                int f = f0 + i, gg = g0 + j;
                M[f][gg] = (cp[f * NF + gg] + acc[i][j] / (float)(NBLK - 1)) * 0.5f;
            }
    }
    if (tid < NF) {
        float d = mu_pris[b * NF + tid] - mu[tid];
        dd[tid] = d;
        M[tid][NF] = d;
    }
    __syncthreads();

    for (int k = 0; k < NF; k++) {
        if (tid < NF && tid != k) facs[tid] = M[tid][k] / M[k][k];
        __syncthreads();
        for (int t = tid; t < NF * (NF + 1); t += 256) {
            int i = t / (NF + 1), j = t % (NF + 1);
            if (i != k && j > k) M[i][j] -= facs[i] * M[k][j];
        }
        __syncthreads();
    }

    if (tid < 64) {
        double c = (tid < NF) ? (double)dd[tid] * ((double)M[tid][NF] / (double)M[tid][tid]) : 0.0;
        #pragma unroll
        for (int off = 32; off > 0; off >>= 1) c += __shfl_down(c, off, 64);
        if (tid == 0) out[b] = (float)sqrt(c);
    }
}

extern "C" void kernel_launch(void* const* d_in, const int* in_sizes, int n_in,
                              void* d_out, int out_size, void* d_ws, size_t ws_size,
                              hipStream_t stream) {
    const float* x        = (const float*)d_in[0];
    const float* mu_pris  = (const float*)d_in[1];
    const float* cov_pris = (const float*)d_in[2];
    float* out = (float*)d_out;
    float* ws  = (float*)d_ws;

    float* y     = ws;                          // NB*H1*W1 = 8,110,080
    float* nrm   = y + (size_t)NB * H1 * W1;    // 8,110,080 (reused: half | nrm2)
    float* rgam  = nrm + (size_t)NB * H1 * W1;  // 9801
    float* ratio = rgam + NGAM;                 // 9801
    float* mfac  = ratio + NGAM;                // 9801
    float* feats = mfac + NGAM;                 // NB*220*36 = 31,680
    float* half  = nrm;                         // NB*H2*W2 = 2,027,520 (after feats96)
    float* nrm2  = half + (size_t)NB * H2 * W2; // 2,027,520

    const int NGB = NB * H1 * (W1 / 4);         // gray items
    k_gray_rgam<<<(NGB + NGAM + 255) / 256, 256, 0, stream>>>(
        (const float4*)x, (float4*)y, rgam, ratio, mfac);

    dim3 thr(32, 8);
    k_mscn<<<dim3(W1 / 32, H1 / 32, NB), thr, 0, stream>>>(y, nrm, H1, W1);
    k_feats<96, 0, 768><<<NB * NBLK, 768, 0, stream>>>(nrm, rgam, ratio, mfac, feats, H1, W1);

    k_resize<<<dim3(W2 / 32, (H2 + 31) / 32, NB), thr, 0, stream>>>(y, half);

    k_mscn<<<dim3(W2 / 32, (H2 + 31) / 32, NB), thr, 0, stream>>>(half, nrm2, H2, W2);
    k_feats<48, 18, 576><<<NB * NBLK, 576, 0, stream>>>(nrm2, rgam, ratio, mfac, feats, H2, W2);

    k_stats<<<NB, 256, 0, stream>>>(feats, mu_pris, cov_pris, out);
}

// Round 10
// 205.076 us; speedup vs baseline: 1.2419x; 1.0903x over previous
//
#include <hip/hip_runtime.h>
#include <math.h>

#define NB   4
#define H1   1056
#define W1   1920
#define H2   528
#define W2   960
#define NBLK 220    // 11*20 blocks per image, both scales
#define NBW  20
#define NF   36
#define NGAM 9801

__device__ __forceinline__ int reflect_idx(int i, int n) {
    if (i < 0) return -i - 1;
    if (i >= n) return 2 * n - i - 1;
    return i;
}

// ---------------- gray (float4 streaming) + R_GAM/ratio/meanfac tables in one launch.
__global__ void k_gray_rgam(const float4* __restrict__ x, float4* __restrict__ y,
                            float* __restrict__ rg, float* __restrict__ rt,
                            float* __restrict__ mf) {
    const int W4 = W1 / 4;
    const int gtotal = NB * H1 * W4;
    int idx = blockIdx.x * 256 + threadIdx.x;
    if (idx < gtotal) {
        int w4 = idx % W4;
        int t  = idx / W4;
        int h  = t % H1;
        int b  = t / H1;
        size_t base = ((size_t)(b * 3) * 1080 + h) * W4 + w4;
        float4 r  = x[base];
        float4 g  = x[base + (size_t)1080 * W4];
        float4 bb = x[base + (size_t)2 * 1080 * W4];
        float4 o;
        o.x = rintf((0.299f * r.x + 0.587f * g.x + 0.114f * bb.x) * 255.0f);
        o.y = rintf((0.299f * r.y + 0.587f * g.y + 0.114f * bb.y) * 255.0f);
        o.z = rintf((0.299f * r.z + 0.587f * g.z + 0.114f * bb.z) * 255.0f);
        o.w = rintf((0.299f * r.w + 0.587f * g.w + 0.114f * bb.w) * 255.0f);
        y[idx] = o;
    } else {
        int i = idx - gtotal;
        if (i < NGAM) {
            float g = (float)i * 0.001f + 0.2f;
            float l1 = lgammaf(1.0f / g);
            float l2 = lgammaf(2.0f / g);
            float l3 = lgammaf(3.0f / g);
            rg[i] = expf(2.0f * l2 - l1 - l3);
            rt[i] = expf(0.5f * (l1 - l3));
            mf[i] = expf(l2 - l1);
        }
    }
}

// ---------------- MSCN, register-blocked separable 7-tap, single-channel input.
// 32x32 output tile, block (32,8); h-pass 4 cols via b128; v-pass 4 rows/thread.
__global__ __launch_bounds__(256) void k_mscn(const float* __restrict__ src,
                                              float* __restrict__ out, int H, int W) {
    __shared__ float tile[38][40];
    __shared__ float h1s[38][36];
    __shared__ float h2s[38][36];
    __shared__ float gw1[8];

    int tx = threadIdx.x;            // 0..31
    int ty = threadIdx.y;            // 0..7
    int tid = ty * 32 + tx;

    if (tid < 7) {
        double s = 7.0 / 6.0;
        double sum = 0.0;
        #pragma unroll
        for (int k = 0; k < 7; k++) sum += exp(-(double)((k - 3) * (k - 3)) / (2.0 * s * s));
        double e = exp(-(double)((tid - 3) * (tid - 3)) / (2.0 * s * s));
        gw1[tid] = (float)(e / sum);
    }

    int b = blockIdx.z;
    const float* p = src + (size_t)b * H * W;
    int ox0 = blockIdx.x * 32, oy0 = blockIdx.y * 32;

    for (int t = tid; t < 38 * 38; t += 256) {
        int r = t / 38, c = t % 38;
        int gr = oy0 - 3 + r; gr = gr < 0 ? 0 : (gr >= H ? H - 1 : gr);
        int gc = ox0 - 3 + c; gc = gc < 0 ? 0 : (gc >= W ? W - 1 : gc);
        tile[r][c] = p[(size_t)gr * W + gc];
    }
    __syncthreads();

    // h-pass: 38 rows x 8 groups of 4 cols
    for (int t = tid; t < 38 * 8; t += 256) {
        int r = t / 8, c0 = (t % 8) * 4;
        float4 f0 = *(const float4*)&tile[r][c0];
        float4 f1 = *(const float4*)&tile[r][c0 + 4];
        float2 f2 = *(const float2*)&tile[r][c0 + 8];
        float v[10] = {f0.x, f0.y, f0.z, f0.w, f1.x, f1.y, f1.z, f1.w, f2.x, f2.y};
        float s1[4] = {0, 0, 0, 0}, s2[4] = {0, 0, 0, 0};
        #pragma unroll
        for (int k = 0; k < 7; k++) {
            float w = gw1[k];
            #pragma unroll
            for (int s = 0; s < 4; s++) {
                float vv = v[s + k];
                s1[s] += w * vv;
                s2[s] += w * vv * vv;
            }
        }
        *(float4*)&h1s[r][c0] = make_float4(s1[0], s1[1], s1[2], s1[3]);
        *(float4*)&h2s[r][c0] = make_float4(s2[0], s2[1], s2[2], s2[3]);
    }
    __syncthreads();

    // v-pass: 4 consecutive rows per thread (register window)
    int ly0 = ty * 4;
    float a1[10], a2[10];
    #pragma unroll
    for (int k = 0; k < 10; k++) { a1[k] = h1s[ly0 + k][tx]; a2[k] = h2s[ly0 + k][tx]; }
    float* q = out + (size_t)b * H * W;
    #pragma unroll
    for (int s = 0; s < 4; s++) {
        int oy = oy0 + ly0 + s, ox = ox0 + tx;
        if (oy < H) {
            float m1 = 0.0f, m2 = 0.0f;
            #pragma unroll
            for (int k = 0; k < 7; k++) {
                float w = gw1[k];
                m1 += w * a1[s + k];
                m2 += w * a2[s + k];
            }
            float sig = sqrtf(fabsf(m2 - m1 * m1));
            q[(size_t)oy * W + ox] = (tile[ly0 + s + 3][tx + 3] - m1) / (sig + 1.0f);
        }
    }
}

// ---------------- fused bicubic half-resize (H then W pass, in LDS): y -> half
__device__ const float RW8[8] = {-0.01171875f, -0.03515625f, 0.11328125f, 0.43359375f,
                                  0.43359375f,  0.11328125f, -0.03515625f, -0.01171875f};

__global__ __launch_bounds__(256) void k_resize(const float* __restrict__ y,
                                                float* __restrict__ half) {
    __shared__ float yt[70][72];
    __shared__ float vv[32][72];
    int tid = threadIdx.y * 32 + threadIdx.x;
    int b = blockIdx.z;
    int j0 = blockIdx.x * 32, i0 = blockIdx.y * 32;
    const float* py = y + (size_t)b * H1 * W1;
    int rbase = 2 * i0 - 3, cbase = 2 * j0 - 3;

    for (int t = tid; t < 70 * 70; t += 256) {
        int r = t / 70, c = t % 70;
        int gr = reflect_idx(rbase + r, H1);
        int gc = reflect_idx(cbase + c, W1);
        yt[r][c] = py[(size_t)gr * W1 + gc] / 255.0f;
    }
    __syncthreads();

    for (int t = tid; t < 32 * 70; t += 256) {
        int i = t / 70, c = t % 70;
        float acc = 0.0f;
        #pragma unroll
        for (int p = 0; p < 8; p++) acc += RW8[p] * yt[2 * i + p][c];
        vv[i][c] = acc;
    }
    __syncthreads();

    float* ph = half + (size_t)b * H2 * W2;
    for (int t = tid; t < 1024; t += 256) {
        int i = t >> 5, j = t & 31;
        int oy = i0 + i, ox = j0 + j;
        if (oy < H2 && ox < W2) {
            float acc = 0.0f;
            #pragma unroll
            for (int p = 0; p < 8; p++) acc += RW8[p] * vv[i][2 * j + p];
            ph[(size_t)oy * W2 + ox] = acc * 255.0f;
        }
    }
}

// ---------------- per-block AGGD features, register-window inner loop, NT=384.
// Both scales run in ONE kernel launch: blocks [0,880) do BS=96 on nrm1,
// blocks [880,1760) do BS=48 on nrm2. Shared memory is a union (96-path size).
template <int BS, int NW>
struct FeatsSmem {
    float x[BS * (BS + 4)];
    float wred[25][NW];
    float sums[25];
    float srn[5], sls[5], srs[5];
    float wargd[5][NW];
    int   wargi[5][NW];
};

template <int BS, int FOFF, int NT>
__device__ __forceinline__ void feats_body(const float* __restrict__ norm,
                                           const float* __restrict__ rgam,
                                           const float* __restrict__ ratio_t,
                                           const float* __restrict__ meanfac_t,
                                           float* __restrict__ feats,
                                           int H, int W, int g, char* smem) {
    constexpr int NW    = NT / 64;
    constexpr int PITCH = BS + 4;
    constexpr int SPAN  = (BS * BS) / NT;   // 24 (96) / 6 (48)
    constexpr int TPR   = BS / SPAN;        // 4 / 8
    static_assert(SPAN % 2 == 0 && TPR * SPAN == BS, "layout");
    auto& S = *reinterpret_cast<FeatsSmem<BS, NW>*>(smem);
    float* x = S.x;

    int b  = g / NBLK;
    int r  = g % NBLK;
    int bh = r / NBW, bw = r % NBW;
    const float* p = norm + (size_t)b * H * W + (size_t)(bh * BS) * W + (size_t)(bw * BS);
    int tid = threadIdx.x;
    int lane = tid & 63, wv = tid >> 6;

    for (int t = tid; t < BS * BS; t += NT) {
        int i = t / BS, j = t - i * BS;
        x[i * PITCH + j] = p[(size_t)i * W + j];
    }
    __syncthreads();

    // per-thread register windows
    int i  = tid / TPR;
    int c0 = (tid % TPR) * SPAN;
    int rowc = i * PITCH;
    int rowm = ((i == 0) ? BS - 1 : i - 1) * PITCH;
    float cv[SPAN], mv[SPAN];
    if constexpr (SPAN % 4 == 0) {
        #pragma unroll
        for (int k = 0; k < SPAN / 4; k++) {
            *(float4*)&cv[4 * k] = *(const float4*)&x[rowc + c0 + 4 * k];
            *(float4*)&mv[4 * k] = *(const float4*)&x[rowm + c0 + 4 * k];
        }
    } else {
        #pragma unroll
        for (int k = 0; k < SPAN / 2; k++) {
            *(float2*)&cv[2 * k] = *(const float2*)&x[rowc + c0 + 2 * k];
            *(float2*)&mv[2 * k] = *(const float2*)&x[rowm + c0 + 2 * k];
        }
    }
    float cprev  = x[rowc + (c0 == 0 ? BS - 1 : c0 - 1)];
    float mleft  = x[rowm + (c0 == 0 ? BS - 1 : c0 - 1)];
    float mright = x[rowm + (c0 + SPAN == BS ? 0 : c0 + SPAN)];

    float sn[5] = {0, 0, 0, 0, 0}, sp[5] = {0, 0, 0, 0, 0};
    float cn[5] = {0, 0, 0, 0, 0}, cp[5] = {0, 0, 0, 0, 0};
    float sa[5] = {0, 0, 0, 0, 0};

    #pragma unroll
    for (int k = 0; k < SPAN; k++) {
        float v0 = cv[k];
        float v[5];
        v[0] = v0;
        v[1] = v0 * (k > 0 ? cv[k - 1] : cprev);
        v[2] = v0 * mv[k];
        v[3] = v0 * (k > 0 ? mv[k - 1] : mleft);
        v[4] = v0 * (k + 1 < SPAN ? mv[k + 1] : mright);
        #pragma unroll
        for (int s = 0; s < 5; s++) {
            float vv = v[s];
            float vn = fminf(vv, 0.0f);
            float vp = fmaxf(vv, 0.0f);
            sn[s] += vn * vn;
            sp[s] += vp * vp;
            cn[s] += (vv < 0.0f) ? 1.0f : 0.0f;
            cp[s] += (vv > 0.0f) ? 1.0f : 0.0f;
            sa[s] += fabsf(vv);
        }
    }

    #pragma unroll
    for (int s = 0; s < 5; s++) {
        float vals[5] = {sn[s], sp[s], cn[s], cp[s], sa[s]};
        #pragma unroll
        for (int m = 0; m < 5; m++) {
            float v = vals[m];
            #pragma unroll
            for (int off = 32; off > 0; off >>= 1) v += __shfl_down(v, off, 64);
            if (lane == 0) S.wred[s * 5 + m][wv] = v;
        }
    }
    __syncthreads();

    if (tid < 25) {
        float s = 0.0f;
        #pragma unroll
        for (int w = 0; w < NW; w++) s += S.wred[tid][w];
        S.sums[tid] = s;
    }
    __syncthreads();

    if (tid < 5) {
        int s = tid;
        float SN = S.sums[s * 5 + 0], SP = S.sums[s * 5 + 1];
        float CN = S.sums[s * 5 + 2], CP = S.sums[s * 5 + 3], SA = S.sums[s * 5 + 4];
        float ls = sqrtf(SN / CN);
        float rs = sqrtf(SP / CP);
        float gh = ls / rs;
        float Nn = (float)(BS * BS);
        float am = SA / Nn;
        float rhat = (am * am) / ((SN + SP) / Nn);
        float g2 = gh * gh;
        float rn = rhat * (g2 * gh + 1.0f) * (gh + 1.0f) / ((g2 + 1.0f) * (g2 + 1.0f));
        S.srn[s] = rn; S.sls[s] = ls; S.srs[s] = rs;
    }
    __syncthreads();

    float bd[5] = {1e30f, 1e30f, 1e30f, 1e30f, 1e30f};
    int   bi[5] = {0, 0, 0, 0, 0};
    float t0 = S.srn[0], t1 = S.srn[1], t2 = S.srn[2], t3 = S.srn[3], t4 = S.srn[4];
    for (int idx = tid; idx < NGAM; idx += NT) {
        float rg = rgam[idx];
        float d0 = (rg - t0) * (rg - t0);
        float d1 = (rg - t1) * (rg - t1);
        float d2 = (rg - t2) * (rg - t2);
        float d3 = (rg - t3) * (rg - t3);
        float d4 = (rg - t4) * (rg - t4);
        if (d0 < bd[0]) { bd[0] = d0; bi[0] = idx; }
        if (d1 < bd[1]) { bd[1] = d1; bi[1] = idx; }
        if (d2 < bd[2]) { bd[2] = d2; bi[2] = idx; }
        if (d3 < bd[3]) { bd[3] = d3; bi[3] = idx; }
        if (d4 < bd[4]) { bd[4] = d4; bi[4] = idx; }
    }
    #pragma unroll
    for (int s = 0; s < 5; s++) {
        float d = bd[s];
        int   ii = bi[s];
        #pragma unroll
        for (int off = 32; off > 0; off >>= 1) {
            float od = __shfl_down(d, off, 64);
            int   oi = __shfl_down(ii, off, 64);
            if (od < d || (od == d && oi < ii)) { d = od; ii = oi; }
        }
        if (lane == 0) { S.wargd[s][wv] = d; S.wargi[s][wv] = ii; }
    }
    __syncthreads();

    if (tid < 5) {
        int s = tid;
        float d = S.wargd[s][0]; int ix = S.wargi[s][0];
        #pragma unroll
        for (int w = 1; w < NW; w++) {
            float od = S.wargd[s][w]; int oi = S.wargi[s][w];
            if (od < d || (od == d && oi < ix)) { d = od; ix = oi; }
        }
        float a = (float)ix * 0.001f + 0.2f;
        float ratio = ratio_t[ix];
        float bl = S.sls[s] * ratio;
        float br = S.srs[s] * ratio;
        float* fp = feats + (size_t)g * NF + FOFF;
        if (s == 0) {
            fp[0] = a; fp[1] = 0.5f * (bl + br);
        } else {
            float mn = (br - bl) * meanfac_t[ix];
            int base = 2 + (s - 1) * 4;
            fp[base] = a; fp[base + 1] = mn; fp[base + 2] = bl; fp[base + 3] = br;
        }
    }
}

__global__ __launch_bounds__(384) void k_feats_both(const float* __restrict__ nrm1,
                                                    const float* __restrict__ nrm2,
                                                    const float* __restrict__ rgam,
                                                    const float* __restrict__ ratio_t,
                                                    const float* __restrict__ meanfac_t,
                                                    float* __restrict__ feats) {
    __shared__ __align__(16) char smem[sizeof(FeatsSmem<96, 6>)];
    int g = blockIdx.x;
    if (g < NB * NBLK)
        feats_body<96, 0, 384>(nrm1, rgam, ratio_t, meanfac_t, feats, H1, W1, g, smem);
    else
        feats_body<48, 18, 384>(nrm2, rgam, ratio_t, meanfac_t, feats, H2, W2,
                                g - NB * NBLK, smem);
}

// ---------------- per-batch stats: cov via transposed dist + 3x3 register tiles,
// then no-pivot Gauss-Jordan (M is SPD), f32 throughout.
__global__ __launch_bounds__(256) void k_stats(const float* __restrict__ feats,
                                               const float* __restrict__ mu_pris,
                                               const float* __restrict__ cov_pris,
                                               float* __restrict__ out) {
    __shared__ float dist[NBLK * NF];
    __shared__ __align__(16) float distT[NF][228];
    __shared__ float mu[NF];
    __shared__ float M[NF][NF + 1];
    __shared__ float facs[NF];
    __shared__ float dd[NF];

    int b = blockIdx.x, tid = threadIdx.x;
    for (int t = tid; t < NBLK * NF; t += 256) dist[t] = feats[(size_t)b * NBLK * NF + t];
    __syncthreads();
    if (tid < NF) {
        float s = 0.0f;
        for (int n = 0; n < NBLK; n++) s += dist[n * NF + tid];
        mu[tid] = s / (float)NBLK;
    }
    __syncthreads();
    for (int t = tid; t < NF * NBLK; t += 256) {
        int f = t / NBLK, n = t % NBLK;
        distT[f][n] = dist[n * NF + f] - mu[f];
    }
    __syncthreads();

    if (tid < 144) {
        int f0 = (tid / 12) * 3, g0 = (tid % 12) * 3;
        float acc[3][3] = {{0,0,0},{0,0,0},{0,0,0}};
        for (int n = 0; n < NBLK; n += 4) {
            float4 A[3], B[3];
            #pragma unroll
            for (int i = 0; i < 3; i++) A[i] = *(const float4*)&distT[f0 + i][n];
            #pragma unroll
            for (int j = 0; j < 3; j++) B[j] = *(const float4*)&distT[g0 + j][n];
            #pragma unroll
            for (int i = 0; i < 3; i++)
                #pragma unroll
                for (int j = 0; j < 3; j++)
                    acc[i][j] += A[i].x * B[j].x + A[i].y * B[j].y
                               + A[i].z * B[j].z + A[i].w * B[j].w;
        }
        const float* cp = cov_pris + (size_t)b * NF * NF;
        #pragma unroll
        for (int i = 0; i < 3; i++)
            #pragma unroll
            for (int j = 0; j < 3; j++) {
                int f = f0 + i, gg = g0 + j;
                M[f][gg] = (cp[f * NF + gg] + acc[i][j] / (float)(NBLK - 1)) * 0.5f;
            }
    }
    if (tid < NF) {
        float d = mu_pris[b * NF + tid] - mu[tid];
        dd[tid] = d;
        M[tid][NF] = d;
    }
    __syncthreads();

    for (int k = 0; k < NF; k++) {
        if (tid < NF && tid != k) facs[tid] = M[tid][k] / M[k][k];
        __syncthreads();
        for (int t = tid; t < NF * (NF + 1); t += 256) {
            int i = t / (NF + 1), j = t % (NF + 1);
            if (i != k && j > k) M[i][j] -= facs[i] * M[k][j];
        }
        __syncthreads();
    }

    if (tid < 64) {
        double c = (tid < NF) ? (double)dd[tid] * ((double)M[tid][NF] / (double)M[tid][tid]) : 0.0;
        #pragma unroll
        for (int off = 32; off > 0; off >>= 1) c += __shfl_down(c, off, 64);
        if (tid == 0) out[b] = (float)sqrt(c);
    }
}

extern "C" void kernel_launch(void* const* d_in, const int* in_sizes, int n_in,
                              void* d_out, int out_size, void* d_ws, size_t ws_size,
                              hipStream_t stream) {
    const float* x        = (const float*)d_in[0];
    const float* mu_pris  = (const float*)d_in[1];
    const float* cov_pris = (const float*)d_in[2];
    float* out = (float*)d_out;
    float* ws  = (float*)d_ws;

    float* y     = ws;                          // NB*H1*W1 = 8,110,080
    float* nrm   = y + (size_t)NB * H1 * W1;    // 8,110,080
    float* half  = nrm + (size_t)NB * H1 * W1;  // 2,027,520
    float* nrm2  = half + (size_t)NB * H2 * W2; // 2,027,520
    float* rgam  = nrm2 + (size_t)NB * H2 * W2; // 9801
    float* ratio = rgam + NGAM;                 // 9801
    float* mfac  = ratio + NGAM;                // 9801
    float* feats = mfac + NGAM;                 // NB*220*36 = 31,680

    const int NGB = NB * H1 * (W1 / 4);         // gray items
    k_gray_rgam<<<(NGB + NGAM + 255) / 256, 256, 0, stream>>>(
        (const float4*)x, (float4*)y, rgam, ratio, mfac);

    dim3 thr(32, 8);
    k_mscn<<<dim3(W1 / 32, H1 / 32, NB), thr, 0, stream>>>(y, nrm, H1, W1);
    k_resize<<<dim3(W2 / 32, (H2 + 31) / 32, NB), thr, 0, stream>>>(y, half);
    k_mscn<<<dim3(W2 / 32, (H2 + 31) / 32, NB), thr, 0, stream>>>(half, nrm2, H2, W2);

    k_feats_both<<<2 * NB * NBLK, 384, 0, stream>>>(nrm, nrm2, rgam, ratio, mfac, feats);

    k_stats<<<NB, 256, 0, stream>>>(feats, mu_pris, cov_pris, out);
}

// Round 11
// 200.129 us; speedup vs baseline: 1.2726x; 1.0247x over previous
//
#include <hip/hip_runtime.h>
#include <math.h>

#define NB   4
#define H1   1056
#define W1   1920
#define H2   528
#define W2   960
#define NBLK 220    // 11*20 blocks per image, both scales
#define NBW  20
#define NF   36
#define NGAM 9801

__device__ __forceinline__ int reflect_idx(int i, int n) {
    if (i < 0) return -i - 1;
    if (i >= n) return 2 * n - i - 1;
    return i;
}

// ---------------- gray (float4 streaming) + R_GAM/ratio/meanfac tables in one launch.
__global__ void k_gray_rgam(const float4* __restrict__ x, float4* __restrict__ y,
                            float* __restrict__ rg, float* __restrict__ rt,
                            float* __restrict__ mf) {
    const int W4 = W1 / 4;
    const int gtotal = NB * H1 * W4;
    int idx = blockIdx.x * 256 + threadIdx.x;
    if (idx < gtotal) {
        int w4 = idx % W4;
        int t  = idx / W4;
        int h  = t % H1;
        int b  = t / H1;
        size_t base = ((size_t)(b * 3) * 1080 + h) * W4 + w4;
        float4 r  = x[base];
        float4 g  = x[base + (size_t)1080 * W4];
        float4 bb = x[base + (size_t)2 * 1080 * W4];
        float4 o;
        o.x = rintf((0.299f * r.x + 0.587f * g.x + 0.114f * bb.x) * 255.0f);
        o.y = rintf((0.299f * r.y + 0.587f * g.y + 0.114f * bb.y) * 255.0f);
        o.z = rintf((0.299f * r.z + 0.587f * g.z + 0.114f * bb.z) * 255.0f);
        o.w = rintf((0.299f * r.w + 0.587f * g.w + 0.114f * bb.w) * 255.0f);
        y[idx] = o;
    } else {
        int i = idx - gtotal;
        if (i < NGAM) {
            float g = (float)i * 0.001f + 0.2f;
            float l1 = lgammaf(1.0f / g);
            float l2 = lgammaf(2.0f / g);
            float l3 = lgammaf(3.0f / g);
            rg[i] = expf(2.0f * l2 - l1 - l3);
            rt[i] = expf(0.5f * (l1 - l3));
            mf[i] = expf(l2 - l1);
        }
    }
}

// ---------------- MSCN, register-blocked separable 7-tap, single-channel input.
// 32x32 output tile, block (32,8); h-pass 4 cols via b128; v-pass 4 rows/thread.
__global__ __launch_bounds__(256) void k_mscn(const float* __restrict__ src,
                                              float* __restrict__ out, int H, int W) {
    __shared__ float tile[38][40];
    __shared__ float h1s[38][36];
    __shared__ float h2s[38][36];
    __shared__ float gw1[8];

    int tx = threadIdx.x;            // 0..31
    int ty = threadIdx.y;            // 0..7
    int tid = ty * 32 + tx;

    if (tid < 7) {
        double s = 7.0 / 6.0;
        double sum = 0.0;
        #pragma unroll
        for (int k = 0; k < 7; k++) sum += exp(-(double)((k - 3) * (k - 3)) / (2.0 * s * s));
        double e = exp(-(double)((tid - 3) * (tid - 3)) / (2.0 * s * s));
        gw1[tid] = (float)(e / sum);
    }

    int b = blockIdx.z;
    const float* p = src + (size_t)b * H * W;
    int ox0 = blockIdx.x * 32, oy0 = blockIdx.y * 32;

    for (int t = tid; t < 38 * 38; t += 256) {
        int r = t / 38, c = t % 38;
        int gr = oy0 - 3 + r; gr = gr < 0 ? 0 : (gr >= H ? H - 1 : gr);
        int gc = ox0 - 3 + c; gc = gc < 0 ? 0 : (gc >= W ? W - 1 : gc);
        tile[r][c] = p[(size_t)gr * W + gc];
    }
    __syncthreads();

    // h-pass: 38 rows x 8 groups of 4 cols
    for (int t = tid; t < 38 * 8; t += 256) {
        int r = t / 8, c0 = (t % 8) * 4;
        float4 f0 = *(const float4*)&tile[r][c0];
        float4 f1 = *(const float4*)&tile[r][c0 + 4];
        float2 f2 = *(const float2*)&tile[r][c0 + 8];
        float v[10] = {f0.x, f0.y, f0.z, f0.w, f1.x, f1.y, f1.z, f1.w, f2.x, f2.y};
        float s1[4] = {0, 0, 0, 0}, s2[4] = {0, 0, 0, 0};
        #pragma unroll
        for (int k = 0; k < 7; k++) {
            float w = gw1[k];
            #pragma unroll
            for (int s = 0; s < 4; s++) {
                float vv = v[s + k];
                s1[s] += w * vv;
                s2[s] += w * vv * vv;
            }
        }
        *(float4*)&h1s[r][c0] = make_float4(s1[0], s1[1], s1[2], s1[3]);
        *(float4*)&h2s[r][c0] = make_float4(s2[0], s2[1], s2[2], s2[3]);
    }
    __syncthreads();

    // v-pass: 4 consecutive rows per thread (register window)
    int ly0 = ty * 4;
    float a1[10], a2[10];
    #pragma unroll
    for (int k = 0; k < 10; k++) { a1[k] = h1s[ly0 + k][tx]; a2[k] = h2s[ly0 + k][tx]; }
    float* q = out + (size_t)b * H * W;
    #pragma unroll
    for (int s = 0; s < 4; s++) {
        int oy = oy0 + ly0 + s, ox = ox0 + tx;
        if (oy < H) {
            float m1 = 0.0f, m2 = 0.0f;
            #pragma unroll
            for (int k = 0; k < 7; k++) {
                float w = gw1[k];
                m1 += w * a1[s + k];
                m2 += w * a2[s + k];
            }
            float sig = sqrtf(fabsf(m2 - m1 * m1));
            q[(size_t)oy * W + ox] = (tile[ly0 + s + 3][tx + 3] - m1) / (sig + 1.0f);
        }
    }
}

// ---------------- fused bicubic half-resize (H then W pass, in LDS): y -> half
__device__ const float RW8[8] = {-0.01171875f, -0.03515625f, 0.11328125f, 0.43359375f,
                                  0.43359375f,  0.11328125f, -0.03515625f, -0.01171875f};

__global__ __launch_bounds__(256) void k_resize(const float* __restrict__ y,
                                                float* __restrict__ half) {
    __shared__ float yt[70][72];
    __shared__ float vv[32][72];
    int tid = threadIdx.y * 32 + threadIdx.x;
    int b = blockIdx.z;
    int j0 = blockIdx.x * 32, i0 = blockIdx.y * 32;
    const float* py = y + (size_t)b * H1 * W1;
    int rbase = 2 * i0 - 3, cbase = 2 * j0 - 3;

    for (int t = tid; t < 70 * 70; t += 256) {
        int r = t / 70, c = t % 70;
        int gr = reflect_idx(rbase + r, H1);
        int gc = reflect_idx(cbase + c, W1);
        yt[r][c] = py[(size_t)gr * W1 + gc] / 255.0f;
    }
    __syncthreads();

    for (int t = tid; t < 32 * 70; t += 256) {
        int i = t / 70, c = t % 70;
        float acc = 0.0f;
        #pragma unroll
        for (int p = 0; p < 8; p++) acc += RW8[p] * yt[2 * i + p][c];
        vv[i][c] = acc;
    }
    __syncthreads();

    float* ph = half + (size_t)b * H2 * W2;
    for (int t = tid; t < 1024; t += 256) {
        int i = t >> 5, j = t & 31;
        int oy = i0 + i, ox = j0 + j;
        if (oy < H2 && ox < W2) {
            float acc = 0.0f;
            #pragma unroll
            for (int p = 0; p < 8; p++) acc += RW8[p] * vv[i][2 * j + p];
            ph[(size_t)oy * W2 + ox] = acc * 255.0f;
        }
    }
}

// ---------------- per-block AGGD features, register windows loaded DIRECTLY from
// global (no LDS image tile -> ~1KB LDS -> high occupancy). NT=384 both scales;
// blocks [0,880) do BS=96 on nrm1, [880,1760) do BS=48 on nrm2.
struct FeatsSmemS {
    float wred[25][6];
    float sums[25];
    float srn[5], sls[5], srs[5];
    float wargd[5][6];
    int   wargi[5][6];
};

template <int BS, int FOFF, int NT>
__device__ __forceinline__ void feats_body(const float* __restrict__ norm,
                                           const float* __restrict__ rgam,
                                           const float* __restrict__ ratio_t,
                                           const float* __restrict__ meanfac_t,
                                           float* __restrict__ feats,
                                           int H, int W, int g, FeatsSmemS& S) {
    constexpr int NW   = NT / 64;
    constexpr int SPAN = (BS * BS) / NT;   // 24 (96) / 6 (48)
    constexpr int TPR  = BS / SPAN;        // 4 / 8
    static_assert(SPAN % 2 == 0 && TPR * SPAN == BS, "layout");

    int b  = g / NBLK;
    int r  = g % NBLK;
    int bh = r / NBW, bw = r % NBW;
    const float* p = norm + (size_t)b * H * W + (size_t)(bh * BS) * W + (size_t)(bw * BS);
    int tid = threadIdx.x;
    int lane = tid & 63, wv = tid >> 6;

    // per-thread register windows straight from global (L2/L3-resident)
    int i  = tid / TPR;
    int c0 = (tid % TPR) * SPAN;
    int im = (i == 0) ? BS - 1 : i - 1;
    const float* rowcp = p + (size_t)i  * W;
    const float* rowmp = p + (size_t)im * W;
    float cv[SPAN], mv[SPAN];
    if constexpr (SPAN % 4 == 0) {
        #pragma unroll
        for (int k = 0; k < SPAN / 4; k++) {
            *(float4*)&cv[4 * k] = *(const float4*)&rowcp[c0 + 4 * k];
            *(float4*)&mv[4 * k] = *(const float4*)&rowmp[c0 + 4 * k];
        }
    } else {
        #pragma unroll
        for (int k = 0; k < SPAN / 2; k++) {
            *(float2*)&cv[2 * k] = *(const float2*)&rowcp[c0 + 2 * k];
            *(float2*)&mv[2 * k] = *(const float2*)&rowmp[c0 + 2 * k];
        }
    }
    float cprev  = rowcp[c0 == 0 ? BS - 1 : c0 - 1];
    float mleft  = rowmp[c0 == 0 ? BS - 1 : c0 - 1];
    float mright = rowmp[c0 + SPAN == BS ? 0 : c0 + SPAN];

    float sn[5] = {0, 0, 0, 0, 0}, sp[5] = {0, 0, 0, 0, 0};
    float cn[5] = {0, 0, 0, 0, 0}, cp[5] = {0, 0, 0, 0, 0};
    float sa[5] = {0, 0, 0, 0, 0};

    #pragma unroll
    for (int k = 0; k < SPAN; k++) {
        float v0 = cv[k];
        float v[5];
        v[0] = v0;
        v[1] = v0 * (k > 0 ? cv[k - 1] : cprev);
        v[2] = v0 * mv[k];
        v[3] = v0 * (k > 0 ? mv[k - 1] : mleft);
        v[4] = v0 * (k + 1 < SPAN ? mv[k + 1] : mright);
        #pragma unroll
        for (int s = 0; s < 5; s++) {
            float vv = v[s];
            float vn = fminf(vv, 0.0f);
            float vp = fmaxf(vv, 0.0f);
            sn[s] += vn * vn;
            sp[s] += vp * vp;
            cn[s] += (vv < 0.0f) ? 1.0f : 0.0f;
            cp[s] += (vv > 0.0f) ? 1.0f : 0.0f;
            sa[s] += fabsf(vv);
        }
    }

    #pragma unroll
    for (int s = 0; s < 5; s++) {
        float vals[5] = {sn[s], sp[s], cn[s], cp[s], sa[s]};
        #pragma unroll
        for (int m = 0; m < 5; m++) {
            float v = vals[m];
            #pragma unroll
            for (int off = 32; off > 0; off >>= 1) v += __shfl_down(v, off, 64);
            if (lane == 0) S.wred[s * 5 + m][wv] = v;
        }
    }
    __syncthreads();

    if (tid < 25) {
        float s = 0.0f;
        #pragma unroll
        for (int w = 0; w < NW; w++) s += S.wred[tid][w];
        S.sums[tid] = s;
    }
    __syncthreads();

    if (tid < 5) {
        int s = tid;
        float SN = S.sums[s * 5 + 0], SP = S.sums[s * 5 + 1];
        float CN = S.sums[s * 5 + 2], CP = S.sums[s * 5 + 3], SA = S.sums[s * 5 + 4];
        float ls = sqrtf(SN / CN);
        float rs = sqrtf(SP / CP);
        float gh = ls / rs;
        float Nn = (float)(BS * BS);
        float am = SA / Nn;
        float rhat = (am * am) / ((SN + SP) / Nn);
        float g2 = gh * gh;
        float rn = rhat * (g2 * gh + 1.0f) * (gh + 1.0f) / ((g2 + 1.0f) * (g2 + 1.0f));
        S.srn[s] = rn; S.sls[s] = ls; S.srs[s] = rs;
    }
    __syncthreads();

    float bd[5] = {1e30f, 1e30f, 1e30f, 1e30f, 1e30f};
    int   bi[5] = {0, 0, 0, 0, 0};
    float t0 = S.srn[0], t1 = S.srn[1], t2 = S.srn[2], t3 = S.srn[3], t4 = S.srn[4];
    for (int idx = tid; idx < NGAM; idx += NT) {
        float rg = rgam[idx];
        float d0 = (rg - t0) * (rg - t0);
        float d1 = (rg - t1) * (rg - t1);
        float d2 = (rg - t2) * (rg - t2);
        float d3 = (rg - t3) * (rg - t3);
        float d4 = (rg - t4) * (rg - t4);
        if (d0 < bd[0]) { bd[0] = d0; bi[0] = idx; }
        if (d1 < bd[1]) { bd[1] = d1; bi[1] = idx; }
        if (d2 < bd[2]) { bd[2] = d2; bi[2] = idx; }
        if (d3 < bd[3]) { bd[3] = d3; bi[3] = idx; }
        if (d4 < bd[4]) { bd[4] = d4; bi[4] = idx; }
    }
    #pragma unroll
    for (int s = 0; s < 5; s++) {
        float d = bd[s];
        int   ii = bi[s];
        #pragma unroll
        for (int off = 32; off > 0; off >>= 1) {
            float od = __shfl_down(d, off, 64);
            int   oi = __shfl_down(ii, off, 64);
            if (od < d || (od == d && oi < ii)) { d = od; ii = oi; }
        }
        if (lane == 0) { S.wargd[s][wv] = d; S.wargi[s][wv] = ii; }
    }
    __syncthreads();

    if (tid < 5) {
        int s = tid;
        float d = S.wargd[s][0]; int ix = S.wargi[s][0];
        #pragma unroll
        for (int w = 1; w < NW; w++) {
            float od = S.wargd[s][w]; int oi = S.wargi[s][w];
            if (od < d || (od == d && oi < ix)) { d = od; ix = oi; }
        }
        float a = (float)ix * 0.001f + 0.2f;
        float ratio = ratio_t[ix];
        float bl = S.sls[s] * ratio;
        float br = S.srs[s] * ratio;
        float* fp = feats + (size_t)g * NF + FOFF;
        if (s == 0) {
            fp[0] = a; fp[1] = 0.5f * (bl + br);
        } else {
            float mn = (br - bl) * meanfac_t[ix];
            int base = 2 + (s - 1) * 4;
            fp[base] = a; fp[base + 1] = mn; fp[base + 2] = bl; fp[base + 3] = br;
        }
    }
}

__global__ __launch_bounds__(384) void k_feats_both(const float* __restrict__ nrm1,
                                                    const float* __restrict__ nrm2,
                                                    const float* __restrict__ rgam,
                                                    const float* __restrict__ ratio_t,
                                                    const float* __restrict__ meanfac_t,
                                                    float* __restrict__ feats) {
    __shared__ FeatsSmemS S;
    int g = blockIdx.x;
    if (g < NB * NBLK)
        feats_body<96, 0, 384>(nrm1, rgam, ratio_t, meanfac_t, feats, H1, W1, g, S);
    else
        feats_body<48, 18, 384>(nrm2, rgam, ratio_t, meanfac_t, feats, H2, W2,
                                g - NB * NBLK, S);
}

// ---------------- per-batch stats: cov via transposed dist + 3x3 register tiles,
// then no-pivot Gauss-Jordan (M is SPD), f32 throughout.
__global__ __launch_bounds__(256) void k_stats(const float* __restrict__ feats,
                                               const float* __restrict__ mu_pris,
                                               const float* __restrict__ cov_pris,
                                               float* __restrict__ out) {
    __shared__ float dist[NBLK * NF];
    __shared__ __align__(16) float distT[NF][228];
    __shared__ float mu[NF];
    __shared__ float M[NF][NF + 1];
    __shared__ float facs[NF];
    __shared__ float dd[NF];

    int b = blockIdx.x, tid = threadIdx.x;
    for (int t = tid; t < NBLK * NF; t += 256) dist[t] = feats[(size_t)b * NBLK * NF + t];
    __syncthreads();
    if (tid < NF) {
        float s = 0.0f;
        for (int n = 0; n < NBLK; n++) s += dist[n * NF + tid];
        mu[tid] = s / (float)NBLK;
    }
    __syncthreads();
    for (int t = tid; t < NF * NBLK; t += 256) {
        int f = t / NBLK, n = t % NBLK;
        distT[f][n] = dist[n * NF + f] - mu[f];
    }
    __syncthreads();

    if (tid < 144) {
        int f0 = (tid / 12) * 3, g0 = (tid % 12) * 3;
        float acc[3][3] = {{0,0,0},{0,0,0},{0,0,0}};
        for (int n = 0; n < NBLK; n += 4) {
            float4 A[3], B[3];
            #pragma unroll
            for (int i = 0; i < 3; i++) A[i] = *(const float4*)&distT[f0 + i][n];
            #pragma unroll
            for (int j = 0; j < 3; j++) B[j] = *(const float4*)&distT[g0 + j][n];
            #pragma unroll
            for (int i = 0; i < 3; i++)
                #pragma unroll
                for (int j = 0; j < 3; j++)
                    acc[i][j] += A[i].x * B[j].x + A[i].y * B[j].y
                               + A[i].z * B[j].z + A[i].w * B[j].w;
        }
        const float* cp = cov_pris + (size_t)b * NF * NF;
        #pragma unroll
        for (int i = 0; i < 3; i++)
            #pragma unroll
            for (int j = 0; j < 3; j++) {
                int f = f0 + i, gg = g0 + j;
                M[f][gg] = (cp[f * NF + gg] + acc[i][j] / (float)(NBLK - 1)) * 0.5f;
            }
    }
    if (tid < NF) {
        float d = mu_pris[b * NF + tid] - mu[tid];
        dd[tid] = d;
        M[tid][NF] = d;
    }
    __syncthreads();

    for (int k = 0; k < NF; k++) {
        if (tid < NF && tid != k) facs[tid] = M[tid][k] / M[k][k];
        __syncthreads();
        for (int t = tid; t < NF * (NF + 1); t += 256) {
            int i = t / (NF + 1), j = t % (NF + 1);
            if (i != k && j > k) M[i][j] -= facs[i] * M[k][j];
        }
        __syncthreads();
    }

    if (tid < 64) {
        double c = (tid < NF) ? (double)dd[tid] * ((double)M[tid][NF] / (double)M[tid][tid]) : 0.0;
        #pragma unroll
        for (int off = 32; off > 0; off >>= 1) c += __shfl_down(c, off, 64);
        if (tid == 0) out[b] = (float)sqrt(c);
    }
}

extern "C" void kernel_launch(void* const* d_in, const int* in_sizes, int n_in,
                              void* d_out, int out_size, void* d_ws, size_t ws_size,
                              hipStream_t stream) {
    const float* x        = (const float*)d_in[0];
    const float* mu_pris  = (const float*)d_in[1];
    const float* cov_pris = (const float*)d_in[2];
    float* out = (float*)d_out;
    float* ws  = (float*)d_ws;

    float* y     = ws;                          // NB*H1*W1 = 8,110,080
    float* nrm   = y + (size_t)NB * H1 * W1;    // 8,110,080
    float* half  = nrm + (size_t)NB * H1 * W1;  // 2,027,520
    float* nrm2  = half + (size_t)NB * H2 * W2; // 2,027,520
    float* rgam  = nrm2 + (size_t)NB * H2 * W2; // 9801
    float* ratio = rgam + NGAM;                 // 9801
    float* mfac  = ratio + NGAM;                // 9801
    float* feats = mfac + NGAM;                 // NB*220*36 = 31,680

    const int NGB = NB * H1 * (W1 / 4);         // gray items
    k_gray_rgam<<<(NGB + NGAM + 255) / 256, 256, 0, stream>>>(
        (const float4*)x, (float4*)y, rgam, ratio, mfac);

    dim3 thr(32, 8);
    k_mscn<<<dim3(W1 / 32, H1 / 32, NB), thr, 0, stream>>>(y, nrm, H1, W1);
    k_resize<<<dim3(W2 / 32, (H2 + 31) / 32, NB), thr, 0, stream>>>(y, half);
    k_mscn<<<dim3(W2 / 32, (H2 + 31) / 32, NB), thr, 0, stream>>>(half, nrm2, H2, W2);

    k_feats_both<<<2 * NB * NBLK, 384, 0, stream>>>(nrm, nrm2, rgam, ratio, mfac, feats);

    k_stats<<<NB, 256, 0, stream>>>(feats, mu_pris, cov_pris, out);
}

// Round 12
// 194.976 us; speedup vs baseline: 1.3062x; 1.0264x over previous
//
#include <hip/hip_runtime.h>
#include <math.h>

#define NB   4
#define H1   1056
#define W1   1920
#define H2   528
#define W2   960
#define NBLK 220    // 11*20 blocks per image, both scales
#define NBW  20
#define NF   36
#define NGAM 9801

__device__ __forceinline__ int reflect_idx(int i, int n) {
    if (i < 0) return -i - 1;
    if (i >= n) return 2 * n - i - 1;
    return i;
}

// ---------------- gray (float4 streaming) + R_GAM/ratio/meanfac tables in one launch.
__global__ void k_gray_rgam(const float4* __restrict__ x, float4* __restrict__ y,
                            float* __restrict__ rg, float* __restrict__ rt,
                            float* __restrict__ mf) {
    const int W4 = W1 / 4;
    const int gtotal = NB * H1 * W4;
    int idx = blockIdx.x * 256 + threadIdx.x;
    if (idx < gtotal) {
        int w4 = idx % W4;
        int t  = idx / W4;
        int h  = t % H1;
        int b  = t / H1;
        size_t base = ((size_t)(b * 3) * 1080 + h) * W4 + w4;
        float4 r  = x[base];
        float4 g  = x[base + (size_t)1080 * W4];
        float4 bb = x[base + (size_t)2 * 1080 * W4];
        float4 o;
        o.x = rintf((0.299f * r.x + 0.587f * g.x + 0.114f * bb.x) * 255.0f);
        o.y = rintf((0.299f * r.y + 0.587f * g.y + 0.114f * bb.y) * 255.0f);
        o.z = rintf((0.299f * r.z + 0.587f * g.z + 0.114f * bb.z) * 255.0f);
        o.w = rintf((0.299f * r.w + 0.587f * g.w + 0.114f * bb.w) * 255.0f);
        y[idx] = o;
    } else {
        int i = idx - gtotal;
        if (i < NGAM) {
            float g = (float)i * 0.001f + 0.2f;
            float l1 = lgammaf(1.0f / g);
            float l2 = lgammaf(2.0f / g);
            float l3 = lgammaf(3.0f / g);
            rg[i] = expf(2.0f * l2 - l1 - l3);
            rt[i] = expf(0.5f * (l1 - l3));
            mf[i] = expf(l2 - l1);
        }
    }
}

// ---------------- MSCN, register-blocked separable 7-tap, single-channel input.
// 32x32 output tile, block (32,8); h-pass 4 cols via b128; v-pass 4 rows/thread.
__global__ __launch_bounds__(256) void k_mscn(const float* __restrict__ src,
                                              float* __restrict__ out, int H, int W) {
    __shared__ float tile[38][40];
    __shared__ float h1s[38][36];
    __shared__ float h2s[38][36];
    __shared__ float gw1[8];

    int tx = threadIdx.x;            // 0..31
    int ty = threadIdx.y;            // 0..7
    int tid = ty * 32 + tx;

    if (tid < 7) {
        double s = 7.0 / 6.0;
        double sum = 0.0;
        #pragma unroll
        for (int k = 0; k < 7; k++) sum += exp(-(double)((k - 3) * (k - 3)) / (2.0 * s * s));
        double e = exp(-(double)((tid - 3) * (tid - 3)) / (2.0 * s * s));
        gw1[tid] = (float)(e / sum);
    }

    int b = blockIdx.z;
    const float* p = src + (size_t)b * H * W;
    int ox0 = blockIdx.x * 32, oy0 = blockIdx.y * 32;

    for (int t = tid; t < 38 * 38; t += 256) {
        int r = t / 38, c = t % 38;
        int gr = oy0 - 3 + r; gr = gr < 0 ? 0 : (gr >= H ? H - 1 : gr);
        int gc = ox0 - 3 + c; gc = gc < 0 ? 0 : (gc >= W ? W - 1 : gc);
        tile[r][c] = p[(size_t)gr * W + gc];
    }
    __syncthreads();

    // h-pass: 38 rows x 8 groups of 4 cols
    for (int t = tid; t < 38 * 8; t += 256) {
        int r = t / 8, c0 = (t % 8) * 4;
        float4 f0 = *(const float4*)&tile[r][c0];
        float4 f1 = *(const float4*)&tile[r][c0 + 4];
        float2 f2 = *(const float2*)&tile[r][c0 + 8];
        float v[10] = {f0.x, f0.y, f0.z, f0.w, f1.x, f1.y, f1.z, f1.w, f2.x, f2.y};
        float s1[4] = {0, 0, 0, 0}, s2[4] = {0, 0, 0, 0};
        #pragma unroll
        for (int k = 0; k < 7; k++) {
            float w = gw1[k];
            #pragma unroll
            for (int s = 0; s < 4; s++) {
                float vv = v[s + k];
                s1[s] += w * vv;
                s2[s] += w * vv * vv;
            }
        }
        *(float4*)&h1s[r][c0] = make_float4(s1[0], s1[1], s1[2], s1[3]);
        *(float4*)&h2s[r][c0] = make_float4(s2[0], s2[1], s2[2], s2[3]);
    }
    __syncthreads();

    // v-pass: 4 consecutive rows per thread (register window)
    int ly0 = ty * 4;
    float a1[10], a2[10];
    #pragma unroll
    for (int k = 0; k < 10; k++) { a1[k] = h1s[ly0 + k][tx]; a2[k] = h2s[ly0 + k][tx]; }
    float* q = out + (size_t)b * H * W;
    #pragma unroll
    for (int s = 0; s < 4; s++) {
        int oy = oy0 + ly0 + s, ox = ox0 + tx;
        if (oy < H) {
            float m1 = 0.0f, m2 = 0.0f;
            #pragma unroll
            for (int k = 0; k < 7; k++) {
                float w = gw1[k];
                m1 += w * a1[s + k];
                m2 += w * a2[s + k];
            }
            float sig = sqrtf(fabsf(m2 - m1 * m1));
            q[(size_t)oy * W + ox] = (tile[ly0 + s + 3][tx + 3] - m1) / (sig + 1.0f);
        }
    }
}

// ---------------- fused bicubic half-resize (H then W pass, in LDS): y -> half
__device__ const float RW8[8] = {-0.01171875f, -0.03515625f, 0.11328125f, 0.43359375f,
                                  0.43359375f,  0.11328125f, -0.03515625f, -0.01171875f};

__global__ __launch_bounds__(256) void k_resize(const float* __restrict__ y,
                                                float* __restrict__ half) {
    __shared__ float yt[70][72];
    __shared__ float vv[32][72];
    int tid = threadIdx.y * 32 + threadIdx.x;
    int b = blockIdx.z;
    int j0 = blockIdx.x * 32, i0 = blockIdx.y * 32;
    const float* py = y + (size_t)b * H1 * W1;
    int rbase = 2 * i0 - 3, cbase = 2 * j0 - 3;

    for (int t = tid; t < 70 * 70; t += 256) {
        int r = t / 70, c = t % 70;
        int gr = reflect_idx(rbase + r, H1);
        int gc = reflect_idx(cbase + c, W1);
        yt[r][c] = py[(size_t)gr * W1 + gc] / 255.0f;
    }
    __syncthreads();

    for (int t = tid; t < 32 * 70; t += 256) {
        int i = t / 70, c = t % 70;
        float acc = 0.0f;
        #pragma unroll
        for (int p = 0; p < 8; p++) acc += RW8[p] * yt[2 * i + p][c];
        vv[i][c] = acc;
    }
    __syncthreads();

    float* ph = half + (size_t)b * H2 * W2;
    for (int t = tid; t < 1024; t += 256) {
        int i = t >> 5, j = t & 31;
        int oy = i0 + i, ox = j0 + j;
        if (oy < H2 && ox < W2) {
            float acc = 0.0f;
            #pragma unroll
            for (int p = 0; p < 8; p++) acc += RW8[p] * vv[i][2 * j + p];
            ph[(size_t)oy * W2 + ox] = acc * 255.0f;
        }
    }
}

// ---------------- per-block AGGD features: chunk-pipelined register windows
// (max per-thread array = 4 floats -> NO scratch spill), loads direct from global.
// NT=384 both scales; blocks [0,880) BS=96 on nrm1, [880,1760) BS=48 on nrm2.
struct FeatsSmemS {
    float wred[25][6];
    float sums[25];
    float srn[5], sls[5], srs[5];
    float wargd[5][6];
    int   wargi[5][6];
};

template <int CW>
__device__ __forceinline__ void loadv(float* d, const float* s) {
    if constexpr (CW == 4) {
        float4 v = *(const float4*)s;
        d[0] = v.x; d[1] = v.y; d[2] = v.z; d[3] = v.w;
    } else {
        float2 v = *(const float2*)s;
        d[0] = v.x; d[1] = v.y;
    }
}

template <int BS, int FOFF, int NT>
__device__ __forceinline__ void feats_body(const float* __restrict__ norm,
                                           const float* __restrict__ rgam,
                                           const float* __restrict__ ratio_t,
                                           const float* __restrict__ meanfac_t,
                                           float* __restrict__ feats,
                                           int H, int W, int g, FeatsSmemS& S) {
    constexpr int NW   = NT / 64;
    constexpr int SPAN = (BS * BS) / NT;        // 24 (96) / 6 (48)
    constexpr int TPR  = BS / SPAN;             // 4 / 8
    constexpr int CW   = (SPAN % 4 == 0) ? 4 : 2;
    constexpr int NCH  = SPAN / CW;             // 6 / 3
    static_assert(TPR * SPAN == BS && NCH * CW == SPAN && NCH >= 2, "layout");

    int b  = g / NBLK;
    int r  = g % NBLK;
    int bh = r / NBW, bw = r % NBW;
    const float* p = norm + (size_t)b * H * W + (size_t)(bh * BS) * W + (size_t)(bw * BS);
    int tid = threadIdx.x;
    int lane = tid & 63, wv = tid >> 6;

    int i  = tid / TPR;
    int c0 = (tid % TPR) * SPAN;
    int im = (i == 0) ? BS - 1 : i - 1;
    const float* rowcp = p + (size_t)i  * W;
    const float* rowmp = p + (size_t)im * W;

    float cprev   = rowcp[c0 == 0 ? BS - 1 : c0 - 1];
    float mprev   = rowmp[c0 == 0 ? BS - 1 : c0 - 1];
    float mrightE = rowmp[c0 + SPAN == BS ? 0 : c0 + SPAN];

    float sn[5] = {0, 0, 0, 0, 0}, sp[5] = {0, 0, 0, 0, 0};
    float cn[5] = {0, 0, 0, 0, 0}, cp[5] = {0, 0, 0, 0, 0};
    float sa[5] = {0, 0, 0, 0, 0};

    float cc[CW], mc[CW], mnx[CW];
    loadv<CW>(mc, rowmp + c0);
    #pragma unroll
    for (int j = 0; j < NCH; j++) {
        loadv<CW>(cc, rowcp + c0 + j * CW);
        if (j + 1 < NCH) loadv<CW>(mnx, rowmp + c0 + (j + 1) * CW);
        float mright_j = (j + 1 < NCH) ? mnx[0] : mrightE;
        #pragma unroll
        for (int k = 0; k < CW; k++) {
            float v0 = cc[k];
            float cl = (k > 0) ? cc[k - 1] : cprev;
            float mk = mc[k];
            float ml = (k > 0) ? mc[k - 1] : mprev;
            float mr = (k + 1 < CW) ? mc[k + 1] : mright_j;
            float v[5] = {v0, v0 * cl, v0 * mk, v0 * ml, v0 * mr};
            #pragma unroll
            for (int s = 0; s < 5; s++) {
                float vv = v[s];
                float vn = fminf(vv, 0.0f);
                float vp = fmaxf(vv, 0.0f);
                sn[s] += vn * vn;
                sp[s] += vp * vp;
                cn[s] += (vv < 0.0f) ? 1.0f : 0.0f;
                cp[s] += (vv > 0.0f) ? 1.0f : 0.0f;
                sa[s] += fabsf(vv);
            }
        }
        cprev = cc[CW - 1];
        mprev = mc[CW - 1];
        #pragma unroll
        for (int k2 = 0; k2 < CW; k2++) mc[k2] = mnx[k2];
    }

    #pragma unroll
    for (int s = 0; s < 5; s++) {
        float vals[5] = {sn[s], sp[s], cn[s], cp[s], sa[s]};
        #pragma unroll
        for (int m = 0; m < 5; m++) {
            float v = vals[m];
            #pragma unroll
            for (int off = 32; off > 0; off >>= 1) v += __shfl_down(v, off, 64);
            if (lane == 0) S.wred[s * 5 + m][wv] = v;
        }
    }
    __syncthreads();

    if (tid < 25) {
        float s = 0.0f;
        #pragma unroll
        for (int w = 0; w < NW; w++) s += S.wred[tid][w];
        S.sums[tid] = s;
    }
    __syncthreads();

    if (tid < 5) {
        int s = tid;
        float SN = S.sums[s * 5 + 0], SP = S.sums[s * 5 + 1];
        float CN = S.sums[s * 5 + 2], CP = S.sums[s * 5 + 3], SA = S.sums[s * 5 + 4];
        float ls = sqrtf(SN / CN);
        float rs = sqrtf(SP / CP);
        float gh = ls / rs;
        float Nn = (float)(BS * BS);
        float am = SA / Nn;
        float rhat = (am * am) / ((SN + SP) / Nn);
        float g2 = gh * gh;
        float rn = rhat * (g2 * gh + 1.0f) * (gh + 1.0f) / ((g2 + 1.0f) * (g2 + 1.0f));
        S.srn[s] = rn; S.sls[s] = ls; S.srs[s] = rs;
    }
    __syncthreads();

    float bd[5] = {1e30f, 1e30f, 1e30f, 1e30f, 1e30f};
    int   bi[5] = {0, 0, 0, 0, 0};
    float t0 = S.srn[0], t1 = S.srn[1], t2 = S.srn[2], t3 = S.srn[3], t4 = S.srn[4];
    #pragma unroll 4
    for (int idx = tid; idx < NGAM; idx += NT) {
        float rg = rgam[idx];
        float d0 = (rg - t0) * (rg - t0);
        float d1 = (rg - t1) * (rg - t1);
        float d2 = (rg - t2) * (rg - t2);
        float d3 = (rg - t3) * (rg - t3);
        float d4 = (rg - t4) * (rg - t4);
        if (d0 < bd[0]) { bd[0] = d0; bi[0] = idx; }
        if (d1 < bd[1]) { bd[1] = d1; bi[1] = idx; }
        if (d2 < bd[2]) { bd[2] = d2; bi[2] = idx; }
        if (d3 < bd[3]) { bd[3] = d3; bi[3] = idx; }
        if (d4 < bd[4]) { bd[4] = d4; bi[4] = idx; }
    }
    #pragma unroll
    for (int s = 0; s < 5; s++) {
        float d = bd[s];
        int   ii = bi[s];
        #pragma unroll
        for (int off = 32; off > 0; off >>= 1) {
            float od = __shfl_down(d, off, 64);
            int   oi = __shfl_down(ii, off, 64);
            if (od < d || (od == d && oi < ii)) { d = od; ii = oi; }
        }
        if (lane == 0) { S.wargd[s][wv] = d; S.wargi[s][wv] = ii; }
    }
    __syncthreads();

    if (tid < 5) {
        int s = tid;
        float d = S.wargd[s][0]; int ix = S.wargi[s][0];
        #pragma unroll
        for (int w = 1; w < NW; w++) {
            float od = S.wargd[s][w]; int oi = S.wargi[s][w];
            if (od < d || (od == d && oi < ix)) { d = od; ix = oi; }
        }
        float a = (float)ix * 0.001f + 0.2f;
        float ratio = ratio_t[ix];
        float bl = S.sls[s] * ratio;
        float br = S.srs[s] * ratio;
        float* fp = feats + (size_t)g * NF + FOFF;
        if (s == 0) {
            fp[0] = a; fp[1] = 0.5f * (bl + br);
        } else {
            float mn = (br - bl) * meanfac_t[ix];
            int base = 2 + (s - 1) * 4;
            fp[base] = a; fp[base + 1] = mn; fp[base + 2] = bl; fp[base + 3] = br;
        }
    }
}

__global__ __launch_bounds__(384, 4) void k_feats_both(const float* __restrict__ nrm1,
                                                       const float* __restrict__ nrm2,
                                                       const float* __restrict__ rgam,
                                                       const float* __restrict__ ratio_t,
                                                       const float* __restrict__ meanfac_t,
                                                       float* __restrict__ feats) {
    __shared__ FeatsSmemS S;
    int g = blockIdx.x;
    if (g < NB * NBLK)
        feats_body<96, 0, 384>(nrm1, rgam, ratio_t, meanfac_t, feats, H1, W1, g, S);
    else
        feats_body<48, 18, 384>(nrm2, rgam, ratio_t, meanfac_t, feats, H2, W2,
                                g - NB * NBLK, S);
}

// ---------------- per-batch stats: cov via transposed dist + 3x3 register tiles,
// then no-pivot Gauss-Jordan (M is SPD), f32 throughout.
__global__ __launch_bounds__(256) void k_stats(const float* __restrict__ feats,
                                               const float* __restrict__ mu_pris,
                                               const float* __restrict__ cov_pris,
                                               float* __restrict__ out) {
    __shared__ float dist[NBLK * NF];
    __shared__ __align__(16) float distT[NF][228];
    __shared__ float mu[NF];
    __shared__ float M[NF][NF + 1];
    __shared__ float facs[NF];
    __shared__ float dd[NF];

    int b = blockIdx.x, tid = threadIdx.x;
    for (int t = tid; t < NBLK * NF; t += 256) dist[t] = feats[(size_t)b * NBLK * NF + t];
    __syncthreads();
    if (tid < NF) {
        float s = 0.0f;
        for (int n = 0; n < NBLK; n++) s += dist[n * NF + tid];
        mu[tid] = s / (float)NBLK;
    }
    __syncthreads();
    for (int t = tid; t < NF * NBLK; t += 256) {
        int f = t / NBLK, n = t % NBLK;
        distT[f][n] = dist[n * NF + f] - mu[f];
    }
    __syncthreads();

    if (tid < 144) {
        int f0 = (tid / 12) * 3, g0 = (tid % 12) * 3;
        float acc[3][3] = {{0,0,0},{0,0,0},{0,0,0}};
        for (int n = 0; n < NBLK; n += 4) {
            float4 A[3], B[3];
            #pragma unroll
            for (int i = 0; i < 3; i++) A[i] = *(const float4*)&distT[f0 + i][n];
            #pragma unroll
            for (int j = 0; j < 3; j++) B[j] = *(const float4*)&distT[g0 + j][n];
            #pragma unroll
            for (int i = 0; i < 3; i++)
                #pragma unroll
                for (int j = 0; j < 3; j++)
                    acc[i][j] += A[i].x * B[j].x + A[i].y * B[j].y
                               + A[i].z * B[j].z + A[i].w * B[j].w;
        }
        const float* cp = cov_pris + (size_t)b * NF * NF;
        #pragma unroll
        for (int i = 0; i < 3; i++)
            #pragma unroll
            for (int j = 0; j < 3; j++) {
                int f = f0 + i, gg = g0 + j;
                M[f][gg] = (cp[f * NF + gg] + acc[i][j] / (float)(NBLK - 1)) * 0.5f;
            }
    }
    if (tid < NF) {
        float d = mu_pris[b * NF + tid] - mu[tid];
        dd[tid] = d;
        M[tid][NF] = d;
    }
    __syncthreads();

    for (int k = 0; k < NF; k++) {
        if (tid < NF && tid != k) facs[tid] = M[tid][k] / M[k][k];
        __syncthreads();
        for (int t = tid; t < NF * (NF + 1); t += 256) {
            int i = t / (NF + 1), j = t % (NF + 1);
            if (i != k && j > k) M[i][j] -= facs[i] * M[k][j];
        }
        __syncthreads();
    }

    if (tid < 64) {
        double c = (tid < NF) ? (double)dd[tid] * ((double)M[tid][NF] / (double)M[tid][tid]) : 0.0;
        #pragma unroll
        for (int off = 32; off > 0; off >>= 1) c += __shfl_down(c, off, 64);
        if (tid == 0) out[b] = (float)sqrt(c);
    }
}

extern "C" void kernel_launch(void* const* d_in, const int* in_sizes, int n_in,
                              void* d_out, int out_size, void* d_ws, size_t ws_size,
                              hipStream_t stream) {
    const float* x        = (const float*)d_in[0];
    const float* mu_pris  = (const float*)d_in[1];
    const float* cov_pris = (const float*)d_in[2];
    float* out = (float*)d_out;
    float* ws  = (float*)d_ws;

    float* y     = ws;                          // NB*H1*W1 = 8,110,080
    float* nrm   = y + (size_t)NB * H1 * W1;    // 8,110,080
    float* half  = nrm + (size_t)NB * H1 * W1;  // 2,027,520
    float* nrm2  = half + (size_t)NB * H2 * W2; // 2,027,520
    float* rgam  = nrm2 + (size_t)NB * H2 * W2; // 9801
    float* ratio = rgam + NGAM;                 // 9801
    float* mfac  = ratio + NGAM;                // 9801
    float* feats = mfac + NGAM;                 // NB*220*36 = 31,680

    const int NGB = NB * H1 * (W1 / 4);         // gray items
    k_gray_rgam<<<(NGB + NGAM + 255) / 256, 256, 0, stream>>>(
        (const float4*)x, (float4*)y, rgam, ratio, mfac);

    dim3 thr(32, 8);
    k_mscn<<<dim3(W1 / 32, H1 / 32, NB), thr, 0, stream>>>(y, nrm, H1, W1);
    k_resize<<<dim3(W2 / 32, (H2 + 31) / 32, NB), thr, 0, stream>>>(y, half);
    k_mscn<<<dim3(W2 / 32, (H2 + 31) / 32, NB), thr, 0, stream>>>(half, nrm2, H2, W2);

    k_feats_both<<<2 * NB * NBLK, 384, 0, stream>>>(nrm, nrm2, rgam, ratio, mfac, feats);

    k_stats<<<NB, 256, 0, stream>>>(feats, mu_pris, cov_pris, out);
}

// Round 13
// 189.805 us; speedup vs baseline: 1.3418x; 1.0272x over previous
//
#include <hip/hip_runtime.h>
#include <math.h>

#define NB   4
#define H1   1056
#define W1   1920
#define H2   528
#define W2   960
#define NBLK 220    // 11*20 blocks per image, both scales
#define NBW  20
#define NF   36
#define NGAM 9801

__device__ __forceinline__ int reflect_idx(int i, int n) {
    if (i < 0) return -i - 1;
    if (i >= n) return 2 * n - i - 1;
    return i;
}

// ---------------- gray (float4 streaming) + R_GAM/ratio/meanfac tables in one launch.
__global__ void k_gray_rgam(const float4* __restrict__ x, float4* __restrict__ y,
                            float* __restrict__ rg, float* __restrict__ rt,
                            float* __restrict__ mf) {
    const int W4 = W1 / 4;
    const int gtotal = NB * H1 * W4;
    int idx = blockIdx.x * 256 + threadIdx.x;
    if (idx < gtotal) {
        int w4 = idx % W4;
        int t  = idx / W4;
        int h  = t % H1;
        int b  = t / H1;
        size_t base = ((size_t)(b * 3) * 1080 + h) * W4 + w4;
        float4 r  = x[base];
        float4 g  = x[base + (size_t)1080 * W4];
        float4 bb = x[base + (size_t)2 * 1080 * W4];
        float4 o;
        o.x = rintf((0.299f * r.x + 0.587f * g.x + 0.114f * bb.x) * 255.0f);
        o.y = rintf((0.299f * r.y + 0.587f * g.y + 0.114f * bb.y) * 255.0f);
        o.z = rintf((0.299f * r.z + 0.587f * g.z + 0.114f * bb.z) * 255.0f);
        o.w = rintf((0.299f * r.w + 0.587f * g.w + 0.114f * bb.w) * 255.0f);
        y[idx] = o;
    } else {
        int i = idx - gtotal;
        if (i < NGAM) {
            float g = (float)i * 0.001f + 0.2f;
            float l1 = lgammaf(1.0f / g);
            float l2 = lgammaf(2.0f / g);
            float l3 = lgammaf(3.0f / g);
            rg[i] = expf(2.0f * l2 - l1 - l3);
            rt[i] = expf(0.5f * (l1 - l3));
            mf[i] = expf(l2 - l1);
        }
    }
}

// ---------------- MSCN, register-blocked separable 7-tap, single-channel input.
// 32x32 output tile, block (32,8); h-pass 4 cols via b128; v-pass 4 rows/thread.
__global__ __launch_bounds__(256) void k_mscn(const float* __restrict__ src,
                                              float* __restrict__ out, int H, int W) {
    __shared__ float tile[38][40];
    __shared__ float h1s[38][36];
    __shared__ float h2s[38][36];
    __shared__ float gw1[8];

    int tx = threadIdx.x;            // 0..31
    int ty = threadIdx.y;            // 0..7
    int tid = ty * 32 + tx;

    if (tid < 7) {
        double s = 7.0 / 6.0;
        double sum = 0.0;
        #pragma unroll
        for (int k = 0; k < 7; k++) sum += exp(-(double)((k - 3) * (k - 3)) / (2.0 * s * s));
        double e = exp(-(double)((tid - 3) * (tid - 3)) / (2.0 * s * s));
        gw1[tid] = (float)(e / sum);
    }

    int b = blockIdx.z;
    const float* p = src + (size_t)b * H * W;
    int ox0 = blockIdx.x * 32, oy0 = blockIdx.y * 32;

    for (int t = tid; t < 38 * 38; t += 256) {
        int r = t / 38, c = t % 38;
        int gr = oy0 - 3 + r; gr = gr < 0 ? 0 : (gr >= H ? H - 1 : gr);
        int gc = ox0 - 3 + c; gc = gc < 0 ? 0 : (gc >= W ? W - 1 : gc);
        tile[r][c] = p[(size_t)gr * W + gc];
    }
    __syncthreads();

    // h-pass: 38 rows x 8 groups of 4 cols
    for (int t = tid; t < 38 * 8; t += 256) {
        int r = t / 8, c0 = (t % 8) * 4;
        float4 f0 = *(const float4*)&tile[r][c0];
        float4 f1 = *(const float4*)&tile[r][c0 + 4];
        float2 f2 = *(const float2*)&tile[r][c0 + 8];
        float v[10] = {f0.x, f0.y, f0.z, f0.w, f1.x, f1.y, f1.z, f1.w, f2.x, f2.y};
        float s1[4] = {0, 0, 0, 0}, s2[4] = {0, 0, 0, 0};
        #pragma unroll
        for (int k = 0; k < 7; k++) {
            float w = gw1[k];
            #pragma unroll
            for (int s = 0; s < 4; s++) {
                float vv = v[s + k];
                s1[s] += w * vv;
                s2[s] += w * vv * vv;
            }
        }
        *(float4*)&h1s[r][c0] = make_float4(s1[0], s1[1], s1[2], s1[3]);
        *(float4*)&h2s[r][c0] = make_float4(s2[0], s2[1], s2[2], s2[3]);
    }
    __syncthreads();

    // v-pass: 4 consecutive rows per thread (register window)
    int ly0 = ty * 4;
    float a1[10], a2[10];
    #pragma unroll
    for (int k = 0; k < 10; k++) { a1[k] = h1s[ly0 + k][tx]; a2[k] = h2s[ly0 + k][tx]; }
    float* q = out + (size_t)b * H * W;
    #pragma unroll
    for (int s = 0; s < 4; s++) {
        int oy = oy0 + ly0 + s, ox = ox0 + tx;
        if (oy < H) {
            float m1 = 0.0f, m2 = 0.0f;
            #pragma unroll
            for (int k = 0; k < 7; k++) {
                float w = gw1[k];
                m1 += w * a1[s + k];
                m2 += w * a2[s + k];
            }
            float sig = sqrtf(fabsf(m2 - m1 * m1));
            q[(size_t)oy * W + ox] = (tile[ly0 + s + 3][tx + 3] - m1) / (sig + 1.0f);
        }
    }
}

// ---------------- fused bicubic half-resize (H then W pass, in LDS): y -> half
__device__ const float RW8[8] = {-0.01171875f, -0.03515625f, 0.11328125f, 0.43359375f,
                                  0.43359375f,  0.11328125f, -0.03515625f, -0.01171875f};

__global__ __launch_bounds__(256) void k_resize(const float* __restrict__ y,
                                                float* __restrict__ half) {
    __shared__ float yt[70][72];
    __shared__ float vv[32][72];
    int tid = threadIdx.y * 32 + threadIdx.x;
    int b = blockIdx.z;
    int j0 = blockIdx.x * 32, i0 = blockIdx.y * 32;
    const float* py = y + (size_t)b * H1 * W1;
    int rbase = 2 * i0 - 3, cbase = 2 * j0 - 3;

    for (int t = tid; t < 70 * 70; t += 256) {
        int r = t / 70, c = t % 70;
        int gr = reflect_idx(rbase + r, H1);
        int gc = reflect_idx(cbase + c, W1);
        yt[r][c] = py[(size_t)gr * W1 + gc] / 255.0f;
    }
    __syncthreads();

    for (int t = tid; t < 32 * 70; t += 256) {
        int i = t / 70, c = t % 70;
        float acc = 0.0f;
        #pragma unroll
        for (int p = 0; p < 8; p++) acc += RW8[p] * yt[2 * i + p][c];
        vv[i][c] = acc;
    }
    __syncthreads();

    float* ph = half + (size_t)b * H2 * W2;
    for (int t = tid; t < 1024; t += 256) {
        int i = t >> 5, j = t & 31;
        int oy = i0 + i, ox = j0 + j;
        if (oy < H2 && ox < W2) {
            float acc = 0.0f;
            #pragma unroll
            for (int p = 0; p < 8; p++) acc += RW8[p] * vv[i][2 * j + p];
            ph[(size_t)oy * W2 + ox] = acc * 255.0f;
        }
    }
}

// ---------------- per-block AGGD features v3:
//  - up-row via __shfl_up (halves global loads; only wave-first-row lanes load)
//  - counts via __ballot/popcll on the scalar pipe (drop out of shfl reduction)
//  - sp = Sv2 - sn, cp = nnz - neg (derived)
//  - monotone R_GAM (strictly increasing in gamma) -> 64-lane ballot binary search
//    replaces the 9801-entry scan + argmin reduction. One wave per shift-set.
struct FeatsSmemS {
    float wred[25][6];
    float sums[25];
    float srn[5], sls[5], srs[5];
};

template <int CW>
__device__ __forceinline__ void loadv(float* d, const float* s) {
    if constexpr (CW == 4) {
        float4 v = *(const float4*)s;
        d[0] = v.x; d[1] = v.y; d[2] = v.z; d[3] = v.w;
    } else {
        float2 v = *(const float2*)s;
        d[0] = v.x; d[1] = v.y;
    }
}

template <int BS, int FOFF, int NT>
__device__ __forceinline__ void feats_body(const float* __restrict__ norm,
                                           const float* __restrict__ rgam,
                                           const float* __restrict__ ratio_t,
                                           const float* __restrict__ meanfac_t,
                                           float* __restrict__ feats,
                                           int H, int W, int g, FeatsSmemS& S) {
    constexpr int NW   = NT / 64;
    constexpr int SPAN = (BS * BS) / NT;        // 24 (96) / 6 (48)
    constexpr int TPR  = BS / SPAN;             // 4 / 8
    constexpr int CW   = (SPAN % 4 == 0) ? 4 : 2;
    constexpr int NCH  = SPAN / CW;             // 6 / 3
    static_assert(TPR * SPAN == BS && NCH * CW == SPAN && NCH >= 2, "layout");

    int b  = g / NBLK;
    int r  = g % NBLK;
    int bh = r / NBW, bw = r % NBW;
    const float* p = norm + (size_t)b * H * W + (size_t)(bh * BS) * W + (size_t)(bw * BS);
    int tid = threadIdx.x;
    int lane = tid & 63, wv = tid >> 6;

    int i  = tid / TPR;
    int c0 = (tid % TPR) * SPAN;
    int im = (i == 0) ? BS - 1 : i - 1;
    const float* rowcp = p + (size_t)i  * W;
    const float* rowmp = p + (size_t)im * W;

    float c2 = rowcp[c0 == 0 ? BS - 1 : c0 - 1];   // left of first element
    float m2 = rowmp[c0 == 0 ? BS - 1 : c0 - 1];   // up-left of first element
    float mrightE = rowmp[c0 + SPAN == BS ? 0 : c0 + SPAN];

    float sn[5] = {0, 0, 0, 0, 0}, s2[5] = {0, 0, 0, 0, 0}, sa[5] = {0, 0, 0, 0, 0};
    int cneg[5] = {0, 0, 0, 0, 0}, cnz[5] = {0, 0, 0, 0, 0};

    auto PROC = [&](float v0, float cl, float up, float ul, float ur) {
        float v[5] = {v0, v0 * cl, v0 * up, v0 * ul, v0 * ur};
        #pragma unroll
        for (int s = 0; s < 5; s++) {
            float vv = v[s];
            float t = fminf(vv, 0.0f);
            sn[s] += t * t;
            s2[s] += vv * vv;
            sa[s] += fabsf(vv);
            cneg[s] += (int)__popcll(__ballot(vv < 0.0f));
            cnz[s]  += (int)__popcll(__ballot(vv != 0.0f));
        }
    };

    float c1 = 0.0f, m1 = 0.0f;
    #pragma unroll
    for (int j = 0; j < NCH; j++) {
        float cc[CW], mm[CW];
        loadv<CW>(cc, rowcp + c0 + j * CW);
        #pragma unroll
        for (int k = 0; k < CW; k++) mm[k] = __shfl_up(cc[k], TPR, 64);
        if (lane < TPR) loadv<CW>(mm, rowmp + c0 + j * CW);
        #pragma unroll
        for (int k = 0; k < CW; k++) {
            if (j == 0 && k == 0) { c1 = cc[0]; m1 = mm[0]; }
            else {
                PROC(c1, c2, m1, m2, mm[k]);   // finalize previous element (upright = current m)
                c2 = c1; m2 = m1; c1 = cc[k]; m1 = mm[k];
            }
        }
    }
    PROC(c1, c2, m1, m2, mrightE);             // last element

    // wave reduce {sn, s2, sa}; counts are wave-uniform scalars already
    #pragma unroll
    for (int s = 0; s < 5; s++) {
        float vals[3] = {sn[s], s2[s], sa[s]};
        const int rows[3] = {0, 1, 4};
        #pragma unroll
        for (int m = 0; m < 3; m++) {
            float v = vals[m];
            #pragma unroll
            for (int off = 32; off > 0; off >>= 1) v += __shfl_down(v, off, 64);
            if (lane == 0) S.wred[s * 5 + rows[m]][wv] = v;
        }
        if (lane == 0) {
            S.wred[s * 5 + 2][wv] = (float)cneg[s];
            S.wred[s * 5 + 3][wv] = (float)cnz[s];
        }
    }
    __syncthreads();

    if (tid < 25) {
        float s = 0.0f;
        #pragma unroll
        for (int w = 0; w < NW; w++) s += S.wred[tid][w];
        S.sums[tid] = s;
    }
    __syncthreads();

    if (tid < 5) {
        int s = tid;
        float SN  = S.sums[s * 5 + 0];
        float S2  = S.sums[s * 5 + 1];
        float CN  = S.sums[s * 5 + 2];
        float CNZ = S.sums[s * 5 + 3];
        float SA  = S.sums[s * 5 + 4];
        float SP = S2 - SN;
        float CP = CNZ - CN;
        float ls = sqrtf(SN / CN);
        float rs = sqrtf(SP / CP);
        float gh = ls / rs;
        float Nn = (float)(BS * BS);
        float am = SA / Nn;
        float rhat = (am * am) / (S2 / Nn);
        float g2 = gh * gh;
        float rn = rhat * (g2 * gh + 1.0f) * (gh + 1.0f) / ((g2 + 1.0f) * (g2 + 1.0f));
        S.srn[s] = rn; S.sls[s] = ls; S.srs[s] = rs;
    }
    __syncthreads();

    // 64-lane monotone lower-bound search, one wave per set
    if (wv < 5) {
        int s = wv;
        float rn = S.srn[s];
        int lo = -1, hi = NGAM;   // invariant: rgam[lo] < rn (or lo==-1), rgam[hi] >= rn (or hi==NGAM)
        while (hi - lo > 1) {
            int n = hi - lo - 1;
            int stride = n / 65 + 1;
            int pi = lo + (lane + 1) * stride;
            bool valid = pi < hi;
            float v = valid ? rgam[pi] : 0.0f;
            unsigned long long blw = __ballot(valid && (v < rn));
            int k = __popcll(blw);
            int oldlo = lo;
            lo = oldlo + k * stride;
            int cand = oldlo + (k + 1) * stride;
            if (cand < hi) hi = cand;
        }
        int lb = hi;
        int ix;
        if (lb <= 0) ix = 0;
        else if (lb >= NGAM) ix = NGAM - 1;
        else {
            float dl = rgam[lb - 1] - rn, dr = rgam[lb] - rn;
            ix = (dl * dl <= dr * dr) ? lb - 1 : lb;   // tie -> smaller (jnp.argmin first-min)
        }
        if (lane == 0) {
            float a = (float)ix * 0.001f + 0.2f;
            float ratio = ratio_t[ix];
            float bl = S.sls[s] * ratio;
            float br = S.srs[s] * ratio;
            float* fp = feats + (size_t)g * NF + FOFF;
            if (s == 0) {
                fp[0] = a; fp[1] = 0.5f * (bl + br);
            } else {
                float mn = (br - bl) * meanfac_t[ix];
                int base = 2 + (s - 1) * 4;
                fp[base] = a; fp[base + 1] = mn; fp[base + 2] = bl; fp[base + 3] = br;
            }
        }
    }
}

__global__ __launch_bounds__(384, 4) void k_feats_both(const float* __restrict__ nrm1,
                                                       const float* __restrict__ nrm2,
                                                       const float* __restrict__ rgam,
                                                       const float* __restrict__ ratio_t,
                                                       const float* __restrict__ meanfac_t,
                                                       float* __restrict__ feats) {
    __shared__ FeatsSmemS S;
    int g = blockIdx.x;
    if (g < NB * NBLK)
        feats_body<96, 0, 384>(nrm1, rgam, ratio_t, meanfac_t, feats, H1, W1, g, S);
    else
        feats_body<48, 18, 384>(nrm2, rgam, ratio_t, meanfac_t, feats, H2, W2,
                                g - NB * NBLK, S);
}

// ---------------- per-batch stats: cov via transposed dist + 3x3 register tiles,
// then no-pivot Gauss-Jordan (M is SPD), f32 throughout.
__global__ __launch_bounds__(256) void k_stats(const float* __restrict__ feats,
                                               const float* __restrict__ mu_pris,
                                               const float* __restrict__ cov_pris,
                                               float* __restrict__ out) {
    __shared__ float dist[NBLK * NF];
    __shared__ __align__(16) float distT[NF][228];
    __shared__ float mu[NF];
    __shared__ float M[NF][NF + 1];
    __shared__ float facs[NF];
    __shared__ float dd[NF];

    int b = blockIdx.x, tid = threadIdx.x;
    for (int t = tid; t < NBLK * NF; t += 256) dist[t] = feats[(size_t)b * NBLK * NF + t];
    __syncthreads();
    if (tid < NF) {
        float s = 0.0f;
        for (int n = 0; n < NBLK; n++) s += dist[n * NF + tid];
        mu[tid] = s / (float)NBLK;
    }
    __syncthreads();
    for (int t = tid; t < NF * NBLK; t += 256) {
        int f = t / NBLK, n = t % NBLK;
        distT[f][n] = dist[n * NF + f] - mu[f];
    }
    __syncthreads();

    if (tid < 144) {
        int f0 = (tid / 12) * 3, g0 = (tid % 12) * 3;
        float acc[3][3] = {{0,0,0},{0,0,0},{0,0,0}};
        for (int n = 0; n < NBLK; n += 4) {
            float4 A[3], B[3];
            #pragma unroll
            for (int i = 0; i < 3; i++) A[i] = *(const float4*)&distT[f0 + i][n];
            #pragma unroll
            for (int j = 0; j < 3; j++) B[j] = *(const float4*)&distT[g0 + j][n];
            #pragma unroll
            for (int i = 0; i < 3; i++)
                #pragma unroll
                for (int j = 0; j < 3; j++)
                    acc[i][j] += A[i].x * B[j].x + A[i].y * B[j].y
                               + A[i].z * B[j].z + A[i].w * B[j].w;
        }
        const float* cp = cov_pris + (size_t)b * NF * NF;
        #pragma unroll
        for (int i = 0; i < 3; i++)
            #pragma unroll
            for (int j = 0; j < 3; j++) {
                int f = f0 + i, gg = g0 + j;
                M[f][gg] = (cp[f * NF + gg] + acc[i][j] / (float)(NBLK - 1)) * 0.5f;
            }
    }
    if (tid < NF) {
        float d = mu_pris[b * NF + tid] - mu[tid];
        dd[tid] = d;
        M[tid][NF] = d;
    }
    __syncthreads();

    for (int k = 0; k < NF; k++) {
        if (tid < NF && tid != k) facs[tid] = M[tid][k] / M[k][k];
        __syncthreads();
        for (int t = tid; t < NF * (NF + 1); t += 256) {
            int i = t / (NF + 1), j = t % (NF + 1);
            if (i != k && j > k) M[i][j] -= facs[i] * M[k][j];
        }
        __syncthreads();
    }

    if (tid < 64) {
        double c = (tid < NF) ? (double)dd[tid] * ((double)M[tid][NF] / (double)M[tid][tid]) : 0.0;
        #pragma unroll
        for (int off = 32; off > 0; off >>= 1) c += __shfl_down(c, off, 64);
        if (tid == 0) out[b] = (float)sqrt(c);
    }
}

extern "C" void kernel_launch(void* const* d_in, const int* in_sizes, int n_in,
                              void* d_out, int out_size, void* d_ws, size_t ws_size,
                              hipStream_t stream) {
    const float* x        = (const float*)d_in[0];
    const float* mu_pris  = (const float*)d_in[1];
    const float* cov_pris = (const float*)d_in[2];
    float* out = (float*)d_out;
    float* ws  = (float*)d_ws;

    float* y     = ws;                          // NB*H1*W1 = 8,110,080
    float* nrm   = y + (size_t)NB * H1 * W1;    // 8,110,080
    float* half  = nrm + (size_t)NB * H1 * W1;  // 2,027,520
    float* nrm2  = half + (size_t)NB * H2 * W2; // 2,027,520
    float* rgam  = nrm2 + (size_t)NB * H2 * W2; // 9801
    float* ratio = rgam + NGAM;                 // 9801
    float* mfac  = ratio + NGAM;                // 9801
    float* feats = mfac + NGAM;                 // NB*220*36 = 31,680

    const int NGB = NB * H1 * (W1 / 4);         // gray items
    k_gray_rgam<<<(NGB + NGAM + 255) / 256, 256, 0, stream>>>(
        (const float4*)x, (float4*)y, rgam, ratio, mfac);

    dim3 thr(32, 8);
    k_mscn<<<dim3(W1 / 32, H1 / 32, NB), thr, 0, stream>>>(y, nrm, H1, W1);
    k_resize<<<dim3(W2 / 32, (H2 + 31) / 32, NB), thr, 0, stream>>>(y, half);
    k_mscn<<<dim3(W2 / 32, (H2 + 31) / 32, NB), thr, 0, stream>>>(half, nrm2, H2, W2);

    k_feats_both<<<2 * NB * NBLK, 384, 0, stream>>>(nrm, nrm2, rgam, ratio, mfac, feats);

    k_stats<<<NB, 256, 0, stream>>>(feats, mu_pris, cov_pris, out);
}

// Round 14
// 165.100 us; speedup vs baseline: 1.5426x; 1.1496x over previous
//
#include <hip/hip_runtime.h>
#include <math.h>

#define NB   4
#define H1   1056
#define W1   1920
#define H2   528
#define W2   960
#define NBLK 220    // 11*20 blocks per image, both scales
#define NBW  20
#define NF   36
#define NGAM 9801
#define NSL1 4      // row-slices per 96-block
#define NPART (NB * NBLK * NSL1 + NB * NBLK)   // 3520 + 880 = 4400

__device__ __forceinline__ int reflect_idx(int i, int n) {
    if (i < 0) return -i - 1;
    if (i >= n) return 2 * n - i - 1;
    return i;
}

// ---------------- gray (float4 streaming) + R_GAM/ratio/meanfac tables in one launch.
__global__ void k_gray_rgam(const float4* __restrict__ x, float4* __restrict__ y,
                            float* __restrict__ rg, float* __restrict__ rt,
                            float* __restrict__ mf) {
    const int W4 = W1 / 4;
    const int gtotal = NB * H1 * W4;
    int idx = blockIdx.x * 256 + threadIdx.x;
    if (idx < gtotal) {
        int w4 = idx % W4;
        int t  = idx / W4;
        int h  = t % H1;
        int b  = t / H1;
        size_t base = ((size_t)(b * 3) * 1080 + h) * W4 + w4;
        float4 r  = x[base];
        float4 g  = x[base + (size_t)1080 * W4];
        float4 bb = x[base + (size_t)2 * 1080 * W4];
        float4 o;
        o.x = rintf((0.299f * r.x + 0.587f * g.x + 0.114f * bb.x) * 255.0f);
        o.y = rintf((0.299f * r.y + 0.587f * g.y + 0.114f * bb.y) * 255.0f);
        o.z = rintf((0.299f * r.z + 0.587f * g.z + 0.114f * bb.z) * 255.0f);
        o.w = rintf((0.299f * r.w + 0.587f * g.w + 0.114f * bb.w) * 255.0f);
        y[idx] = o;
    } else {
        int i = idx - gtotal;
        if (i < NGAM) {
            float g = (float)i * 0.001f + 0.2f;
            float l1 = lgammaf(1.0f / g);
            float l2 = lgammaf(2.0f / g);
            float l3 = lgammaf(3.0f / g);
            rg[i] = expf(2.0f * l2 - l1 - l3);
            rt[i] = expf(0.5f * (l1 - l3));
            mf[i] = expf(l2 - l1);
        }
    }
}

// ---------------- MSCN, register-blocked separable 7-tap, single-channel input.
__global__ __launch_bounds__(256) void k_mscn(const float* __restrict__ src,
                                              float* __restrict__ out, int H, int W) {
    __shared__ float tile[38][40];
    __shared__ float h1s[38][36];
    __shared__ float h2s[38][36];
    __shared__ float gw1[8];

    int tx = threadIdx.x;            // 0..31
    int ty = threadIdx.y;            // 0..7
    int tid = ty * 32 + tx;

    if (tid < 7) {
        double s = 7.0 / 6.0;
        double sum = 0.0;
        #pragma unroll
        for (int k = 0; k < 7; k++) sum += exp(-(double)((k - 3) * (k - 3)) / (2.0 * s * s));
        double e = exp(-(double)((tid - 3) * (tid - 3)) / (2.0 * s * s));
        gw1[tid] = (float)(e / sum);
    }

    int b = blockIdx.z;
    const float* p = src + (size_t)b * H * W;
    int ox0 = blockIdx.x * 32, oy0 = blockIdx.y * 32;

    for (int t = tid; t < 38 * 38; t += 256) {
        int r = t / 38, c = t % 38;
        int gr = oy0 - 3 + r; gr = gr < 0 ? 0 : (gr >= H ? H - 1 : gr);
        int gc = ox0 - 3 + c; gc = gc < 0 ? 0 : (gc >= W ? W - 1 : gc);
        tile[r][c] = p[(size_t)gr * W + gc];
    }
    __syncthreads();

    for (int t = tid; t < 38 * 8; t += 256) {
        int r = t / 8, c0 = (t % 8) * 4;
        float4 f0 = *(const float4*)&tile[r][c0];
        float4 f1 = *(const float4*)&tile[r][c0 + 4];
        float2 f2 = *(const float2*)&tile[r][c0 + 8];
        float v[10] = {f0.x, f0.y, f0.z, f0.w, f1.x, f1.y, f1.z, f1.w, f2.x, f2.y};
        float s1[4] = {0, 0, 0, 0}, s2[4] = {0, 0, 0, 0};
        #pragma unroll
        for (int k = 0; k < 7; k++) {
            float w = gw1[k];
            #pragma unroll
            for (int s = 0; s < 4; s++) {
                float vv = v[s + k];
                s1[s] += w * vv;
                s2[s] += w * vv * vv;
            }
        }
        *(float4*)&h1s[r][c0] = make_float4(s1[0], s1[1], s1[2], s1[3]);
        *(float4*)&h2s[r][c0] = make_float4(s2[0], s2[1], s2[2], s2[3]);
    }
    __syncthreads();

    int ly0 = ty * 4;
    float a1[10], a2[10];
    #pragma unroll
    for (int k = 0; k < 10; k++) { a1[k] = h1s[ly0 + k][tx]; a2[k] = h2s[ly0 + k][tx]; }
    float* q = out + (size_t)b * H * W;
    #pragma unroll
    for (int s = 0; s < 4; s++) {
        int oy = oy0 + ly0 + s, ox = ox0 + tx;
        if (oy < H) {
            float m1 = 0.0f, m2 = 0.0f;
            #pragma unroll
            for (int k = 0; k < 7; k++) {
                float w = gw1[k];
                m1 += w * a1[s + k];
                m2 += w * a2[s + k];
            }
            float sig = sqrtf(fabsf(m2 - m1 * m1));
            q[(size_t)oy * W + ox] = (tile[ly0 + s + 3][tx + 3] - m1) / (sig + 1.0f);
        }
    }
}

// ---------------- fused bicubic half-resize (H then W pass, in LDS): y -> half
__device__ const float RW8[8] = {-0.01171875f, -0.03515625f, 0.11328125f, 0.43359375f,
                                  0.43359375f,  0.11328125f, -0.03515625f, -0.01171875f};

__global__ __launch_bounds__(256) void k_resize(const float* __restrict__ y,
                                                float* __restrict__ half) {
    __shared__ float yt[70][72];
    __shared__ float vv[32][72];
    int tid = threadIdx.y * 32 + threadIdx.x;
    int b = blockIdx.z;
    int j0 = blockIdx.x * 32, i0 = blockIdx.y * 32;
    const float* py = y + (size_t)b * H1 * W1;
    int rbase = 2 * i0 - 3, cbase = 2 * j0 - 3;

    for (int t = tid; t < 70 * 70; t += 256) {
        int r = t / 70, c = t % 70;
        int gr = reflect_idx(rbase + r, H1);
        int gc = reflect_idx(cbase + c, W1);
        yt[r][c] = py[(size_t)gr * W1 + gc] / 255.0f;
    }
    __syncthreads();

    for (int t = tid; t < 32 * 70; t += 256) {
        int i = t / 70, c = t % 70;
        float acc = 0.0f;
        #pragma unroll
        for (int p = 0; p < 8; p++) acc += RW8[p] * yt[2 * i + p][c];
        vv[i][c] = acc;
    }
    __syncthreads();

    float* ph = half + (size_t)b * H2 * W2;
    for (int t = tid; t < 1024; t += 256) {
        int i = t >> 5, j = t & 31;
        int oy = i0 + i, ox = j0 + j;
        if (oy < H2 && ox < W2) {
            float acc = 0.0f;
            #pragma unroll
            for (int p = 0; p < 8; p++) acc += RW8[p] * vv[i][2 * j + p];
            ph[(size_t)oy * W2 + ox] = acc * 255.0f;
        }
    }
}

// ---------------- FEATS phase A: per-slice partial stats. 192 threads, 2304 elems.
// 96-scale: 4 slices of 24 rows (TPR=8); 48-scale: whole 48x48 block (TPR=4).
// Up-row via __shfl_up; counts via ballot/popcll; partials -> part[sg][25].
template <int CW>
__device__ __forceinline__ void loadv(float* d, const float* s) {
    float4 v = *(const float4*)s;
    d[0] = v.x; d[1] = v.y; d[2] = v.z; d[3] = v.w;
}

template <int COLS, int TPR>
__device__ __forceinline__ void fpart_body(const float* __restrict__ p, int W,
                                           int row0, int BSfull,
                                           float* __restrict__ outp) {
    constexpr int SPAN = 12, CW = 4, NCH = 3;
    __shared__ float wls[3][25];
    int tid = threadIdx.x, lane = tid & 63, wv = tid >> 6;

    int li = tid / TPR;
    int c0 = (tid % TPR) * SPAN;
    int gi = row0 + li;
    int gim = (gi == 0) ? BSfull - 1 : gi - 1;
    const float* rowcp = p + (size_t)gi * W;
    const float* rowmp = p + (size_t)gim * W;

    float c2 = rowcp[c0 == 0 ? COLS - 1 : c0 - 1];
    float m2 = rowmp[c0 == 0 ? COLS - 1 : c0 - 1];
    float mrightE = rowmp[c0 + SPAN == COLS ? 0 : c0 + SPAN];

    float sn[5] = {0, 0, 0, 0, 0}, s2[5] = {0, 0, 0, 0, 0}, sa[5] = {0, 0, 0, 0, 0};
    int cneg[5] = {0, 0, 0, 0, 0}, cnz[5] = {0, 0, 0, 0, 0};

    auto PROC = [&](float v0, float cl, float up, float ul, float ur) {
        float v[5] = {v0, v0 * cl, v0 * up, v0 * ul, v0 * ur};
        #pragma unroll
        for (int s = 0; s < 5; s++) {
            float vv = v[s];
            float t = fminf(vv, 0.0f);
            sn[s] += t * t;
            s2[s] += vv * vv;
            sa[s] += fabsf(vv);
            cneg[s] += (int)__popcll(__ballot(vv < 0.0f));
            cnz[s]  += (int)__popcll(__ballot(vv != 0.0f));
        }
    };

    float c1 = 0.0f, m1 = 0.0f;
    #pragma unroll
    for (int j = 0; j < NCH; j++) {
        float cc[CW], mm[CW];
        loadv<CW>(cc, rowcp + c0 + j * CW);
        #pragma unroll
        for (int k = 0; k < CW; k++) mm[k] = __shfl_up(cc[k], TPR, 64);
        if (lane < TPR) loadv<CW>(mm, rowmp + c0 + j * CW);
        #pragma unroll
        for (int k = 0; k < CW; k++) {
            if (j == 0 && k == 0) { c1 = cc[0]; m1 = mm[0]; }
            else {
                PROC(c1, c2, m1, m2, mm[k]);
                c2 = c1; m2 = m1; c1 = cc[k]; m1 = mm[k];
            }
        }
    }
    PROC(c1, c2, m1, m2, mrightE);

    // wave reduce {sn, s2, sa}; counts already wave-uniform
    #pragma unroll
    for (int s = 0; s < 5; s++) {
        float vals[3] = {sn[s], s2[s], sa[s]};
        const int rows3[3] = {0, 1, 4};
        #pragma unroll
        for (int m = 0; m < 3; m++) {
            float v = vals[m];
            #pragma unroll
            for (int off = 32; off > 0; off >>= 1) v += __shfl_down(v, off, 64);
            if (lane == 0) wls[wv][s * 5 + rows3[m]] = v;
        }
        if (lane == 0) {
            wls[wv][s * 5 + 2] = (float)cneg[s];
            wls[wv][s * 5 + 3] = (float)cnz[s];
        }
    }
    __syncthreads();
    if (tid < 25) outp[tid] = wls[0][tid] + wls[1][tid] + wls[2][tid];
}

__global__ __launch_bounds__(192) void k_fpart(const float* __restrict__ nrm1,
                                               const float* __restrict__ nrm2,
                                               float* __restrict__ part) {
    int sg = blockIdx.x;
    if (sg < NB * NBLK * NSL1) {
        int g = sg >> 2, sl = sg & 3;
        int b = g / NBLK, r = g % NBLK;
        const float* p = nrm1 + (size_t)b * H1 * W1 + (size_t)(r / NBW * 96) * W1
                       + (size_t)(r % NBW) * 96;
        fpart_body<96, 8>(p, W1, sl * 24, 96, part + (size_t)sg * 25);
    } else {
        int g = sg - NB * NBLK * NSL1;
        int b = g / NBLK, r = g % NBLK;
        const float* p = nrm2 + (size_t)b * H2 * W2 + (size_t)(r / NBW * 48) * W2
                       + (size_t)(r % NBW) * 48;
        fpart_body<48, 4>(p, W2, 0, 48, part + (size_t)sg * 25);
    }
}

// ---------------- FEATS phase B: combine partials, finalize, monotone binary search.
// 1760 one-wave blocks; g<880 -> 96-scale (sum 4 slices), else 48-scale.
__global__ __launch_bounds__(64) void k_ffinal(const float* __restrict__ part,
                                               const float* __restrict__ rgam,
                                               const float* __restrict__ ratio_t,
                                               const float* __restrict__ meanfac_t,
                                               float* __restrict__ feats) {
    __shared__ float ss[25];
    __shared__ float srn[5], sls[5], srs[5];
    int g = blockIdx.x, lane = threadIdx.x;
    int FOFF, BS;
    if (g < NB * NBLK) {
        if (lane < 25) {
            float s = 0.0f;
            #pragma unroll
            for (int sl = 0; sl < NSL1; sl++)
                s += part[(size_t)(g * NSL1 + sl) * 25 + lane];
            ss[lane] = s;
        }
        FOFF = 0; BS = 96;
    } else {
        if (lane < 25) ss[lane] = part[(size_t)(NB * NBLK * NSL1 + (g - NB * NBLK)) * 25 + lane];
        FOFF = 18; BS = 48;
    }
    __syncthreads();

    if (lane < 5) {
        int s = lane;
        float SN  = ss[s * 5 + 0];
        float S2  = ss[s * 5 + 1];
        float CN  = ss[s * 5 + 2];
        float CNZ = ss[s * 5 + 3];
        float SA  = ss[s * 5 + 4];
        float SP = S2 - SN;
        float CP = CNZ - CN;
        float ls = sqrtf(SN / CN);
        float rs = sqrtf(SP / CP);
        float gh = ls / rs;
        float Nn = (float)(BS * BS);
        float am = SA / Nn;
        float rhat = (am * am) / (S2 / Nn);
        float g2 = gh * gh;
        float rn = rhat * (g2 * gh + 1.0f) * (gh + 1.0f) / ((g2 + 1.0f) * (g2 + 1.0f));
        srn[s] = rn; sls[s] = ls; srs[s] = rs;
    }
    __syncthreads();

    int gl = (g < NB * NBLK) ? g : g - NB * NBLK;
    float* fp = feats + (size_t)gl * NF + FOFF;
    for (int s = 0; s < 5; s++) {
        float rn = srn[s];
        int lo = -1, hi = NGAM;
        while (hi - lo > 1) {
            int n = hi - lo - 1;
            int stride = n / 65 + 1;
            int pi = lo + (lane + 1) * stride;
            bool valid = pi < hi;
            float v = valid ? rgam[pi] : 0.0f;
            unsigned long long blw = __ballot(valid && (v < rn));
            int k = __popcll(blw);
            int oldlo = lo;
            lo = oldlo + k * stride;
            int cand = oldlo + (k + 1) * stride;
            if (cand < hi) hi = cand;
        }
        int lb = hi;
        int ix;
        if (lb <= 0) ix = 0;
        else if (lb >= NGAM) ix = NGAM - 1;
        else {
            float dl = rgam[lb - 1] - rn, dr = rgam[lb] - rn;
            ix = (dl * dl <= dr * dr) ? lb - 1 : lb;
        }
        if (lane == 0) {
            float a = (float)ix * 0.001f + 0.2f;
            float ratio = ratio_t[ix];
            float bl = sls[s] * ratio;
            float br = srs[s] * ratio;
            if (s == 0) {
                fp[0] = a; fp[1] = 0.5f * (bl + br);
            } else {
                float mn = (br - bl) * meanfac_t[ix];
                int base = 2 + (s - 1) * 4;
                fp[base] = a; fp[base + 1] = mn; fp[base + 2] = bl; fp[base + 3] = br;
            }
        }
    }
}

// ---------------- per-batch stats: cov via transposed dist + 3x3 register tiles,
// then no-pivot Gauss-Jordan (M is SPD), f32 throughout.
__global__ __launch_bounds__(256) void k_stats(const float* __restrict__ feats,
                                               const float* __restrict__ mu_pris,
                                               const float* __restrict__ cov_pris,
                                               float* __restrict__ out) {
    __shared__ float dist[NBLK * NF];
    __shared__ __align__(16) float distT[NF][228];
    __shared__ float mu[NF];
    __shared__ float M[NF][NF + 1];
    __shared__ float facs[NF];
    __shared__ float dd[NF];

    int b = blockIdx.x, tid = threadIdx.x;
    for (int t = tid; t < NBLK * NF; t += 256) dist[t] = feats[(size_t)b * NBLK * NF + t];
    __syncthreads();
    if (tid < NF) {
        float s = 0.0f;
        for (int n = 0; n < NBLK; n++) s += dist[n * NF + tid];
        mu[tid] = s / (float)NBLK;
    }
    __syncthreads();
    for (int t = tid; t < NF * NBLK; t += 256) {
        int f = t / NBLK, n = t % NBLK;
        distT[f][n] = dist[n * NF + f] - mu[f];
    }
    __syncthreads();

    if (tid < 144) {
        int f0 = (tid / 12) * 3, g0 = (tid % 12) * 3;
        float acc[3][3] = {{0,0,0},{0,0,0},{0,0,0}};
        for (int n = 0; n < NBLK; n += 4) {
            float4 A[3], B[3];
            #pragma unroll
            for (int i = 0; i < 3; i++) A[i] = *(const float4*)&distT[f0 + i][n];
            #pragma unroll
            for (int j = 0; j < 3; j++) B[j] = *(const float4*)&distT[g0 + j][n];
            #pragma unroll
            for (int i = 0; i < 3; i++)
                #pragma unroll
                for (int j = 0; j < 3; j++)
                    acc[i][j] += A[i].x * B[j].x + A[i].y * B[j].y
                               + A[i].z * B[j].z + A[i].w * B[j].w;
        }
        const float* cp = cov_pris + (size_t)b * NF * NF;
        #pragma unroll
        for (int i = 0; i < 3; i++)
            #pragma unroll
            for (int j = 0; j < 3; j++) {
                int f = f0 + i, gg = g0 + j;
                M[f][gg] = (cp[f * NF + gg] + acc[i][j] / (float)(NBLK - 1)) * 0.5f;
            }
    }
    if (tid < NF) {
        float d = mu_pris[b * NF + tid] - mu[tid];
        dd[tid] = d;
        M[tid][NF] = d;
    }
    __syncthreads();

    for (int k = 0; k < NF; k++) {
        if (tid < NF && tid != k) facs[tid] = M[tid][k] / M[k][k];
        __syncthreads();
        for (int t = tid; t < NF * (NF + 1); t += 256) {
            int i = t / (NF + 1), j = t % (NF + 1);
            if (i != k && j > k) M[i][j] -= facs[i] * M[k][j];
        }
        __syncthreads();
    }

    if (tid < 64) {
        double c = (tid < NF) ? (double)dd[tid] * ((double)M[tid][NF] / (double)M[tid][tid]) : 0.0;
        #pragma unroll
        for (int off = 32; off > 0; off >>= 1) c += __shfl_down(c, off, 64);
        if (tid == 0) out[b] = (float)sqrt(c);
    }
}

extern "C" void kernel_launch(void* const* d_in, const int* in_sizes, int n_in,
                              void* d_out, int out_size, void* d_ws, size_t ws_size,
                              hipStream_t stream) {
    const float* x        = (const float*)d_in[0];
    const float* mu_pris  = (const float*)d_in[1];
    const float* cov_pris = (const float*)d_in[2];
    float* out = (float*)d_out;
    float* ws  = (float*)d_ws;

    float* y     = ws;                          // NB*H1*W1 = 8,110,080
    float* nrm   = y + (size_t)NB * H1 * W1;    // 8,110,080
    float* half  = nrm + (size_t)NB * H1 * W1;  // 2,027,520
    float* nrm2  = half + (size_t)NB * H2 * W2; // 2,027,520
    float* rgam  = nrm2 + (size_t)NB * H2 * W2; // 9801
    float* ratio = rgam + NGAM;                 // 9801
    float* mfac  = ratio + NGAM;                // 9801
    float* feats = mfac + NGAM;                 // NB*220*36 = 31,680
    float* part  = feats + (size_t)NB * NBLK * NF;  // 4400*25 = 110,000

    const int NGB = NB * H1 * (W1 / 4);         // gray items
    k_gray_rgam<<<(NGB + NGAM + 255) / 256, 256, 0, stream>>>(
        (const float4*)x, (float4*)y, rgam, ratio, mfac);

    dim3 thr(32, 8);
    k_mscn<<<dim3(W1 / 32, H1 / 32, NB), thr, 0, stream>>>(y, nrm, H1, W1);
    k_resize<<<dim3(W2 / 32, (H2 + 31) / 32, NB), thr, 0, stream>>>(y, half);
    k_mscn<<<dim3(W2 / 32, (H2 + 31) / 32, NB), thr, 0, stream>>>(half, nrm2, H2, W2);

    k_fpart<<<NPART, 192, 0, stream>>>(nrm, nrm2, part);
    k_ffinal<<<2 * NB * NBLK, 64, 0, stream>>>(part, rgam, ratio, mfac, feats);

    k_stats<<<NB, 256, 0, stream>>>(feats, mu_pris, cov_pris, out);
}